// Round 6
// baseline (340.045 us; speedup 1.0000x reference)
//
#include <hip/hip_runtime.h>
#include <hip/hip_bf16.h>

// B=32, S=480, D=512, H=8, dk=64. Outputs: out[32,480,512] fp32,
// attn_mean[32,480,480] fp32, concatenated in d_out.
//
// Pipeline (bf16 MFMA 16x16x32):
//  1. cvt_x      : x fp32 -> bf16
//  2. cvt_w      : w* fp32 [K][N] -> bf16 [N][K]
//  3. qk_gemm    : q/k -> [B,H,S,dk] bf16 (BK=64, XOR-swizzled LDS chunks)
//  4. v_gemm     : transposed gemm -> V TILED: vtil[bh][kt][d][32] (4KB/kt tile)
//  5. cvt_rbt    : rel_bias*log2e -> paired-tiled rbt[h][kt][i][{lm, 16+lm}]
//  6. flash_attn : 32 q-rows/wave, no barriers, no max-tracking (|s|<~3);
//                  straight loop (NO lambdas/reg-dbuf — spills to scratch),
//                  exp2-native prescaled bias, diagonal-only masking,
//                  cvt_pk_bf16 pack, setprio. cst = log2(lsum) [b][i][h].
//  7. attn_mean_k2: recompute S per (i64,j64) tile; K LDS-staged (dbuf 18KB),
//                  bias per-jj TRANSIENT scalar loads from rbt (low VGPR),
//                  __launch_bounds__(256,4) to force >=4 waves/SIMD,
//                  normalization fused into exponent (exp2(s*SCL+b'-c2)).
//  8. out_gemm   : ctx @ woT + bo -> fp32 (BK=64, swizzled)

typedef unsigned short ushort_t;
typedef __attribute__((ext_vector_type(8))) short short8;
typedef __attribute__((ext_vector_type(4))) float floatx4;

#define NB 32
#define NS 480
#define ND 512
#define NH 8
#define NDK 64
#define MAXLEN 500
#define KSTRIDE 72
#define PSTR 36   // sP row stride (ushorts): b128 frag reads <=2-way bank alias
#define SCL 0.18033688f  // 0.125 * log2(e)

__device__ __forceinline__ ushort_t f2bf(float f) {
  union { float f; unsigned u; } v; v.f = f;
  unsigned r = v.u + 0x7FFFu + ((v.u >> 16) & 1u);
  return (ushort_t)(r >> 16);
}

#define GLOAD_LDS16(g, l)                                                      \
  __builtin_amdgcn_global_load_lds(                                            \
      (const __attribute__((address_space(1))) void*)(g),                      \
      (__attribute__((address_space(3))) void*)(l), 16, 0, 0)

// ---------------------------------------------------------------- cvt_x
__global__ void cvt_x(const float* __restrict__ x, ushort_t* __restrict__ xb) {
  int idx = blockIdx.x * 256 + threadIdx.x;
  float4 v = ((const float4*)x)[idx];
  ushort4 o;
  o.x = f2bf(v.x); o.y = f2bf(v.y); o.z = f2bf(v.z); o.w = f2bf(v.w);
  ((ushort4*)xb)[idx] = o;
}

// ---------------------------------------------------------------- cvt_w
__global__ void cvt_w(const float* __restrict__ wq, const float* __restrict__ wk,
                      const float* __restrict__ wv, const float* __restrict__ wo,
                      ushort_t* __restrict__ wqT, ushort_t* __restrict__ wkT,
                      ushort_t* __restrict__ wvT, ushort_t* __restrict__ woT) {
  __shared__ float t[32][33];
  int z = blockIdx.z;
  const float* w = (z == 0) ? wq : (z == 1) ? wk : (z == 2) ? wv : wo;
  ushort_t* wT = (z == 0) ? wqT : (z == 1) ? wkT : (z == 2) ? wvT : woT;
  int k0 = blockIdx.x * 32, n0 = blockIdx.y * 32;
  int tx = threadIdx.x & 31, ty = threadIdx.x >> 5;
#pragma unroll
  for (int yy = 0; yy < 4; ++yy)
    t[ty + yy * 8][tx] = w[(k0 + ty + yy * 8) * ND + n0 + tx];
  __syncthreads();
#pragma unroll
  for (int yy = 0; yy < 4; ++yy)
    wT[(n0 + ty + yy * 8) * ND + k0 + tx] = f2bf(t[tx][ty + yy * 8]);
}

// ---------------------------------------------------------------- cvt_rbt
// rbt[((h*15+kt)*480 + i)*32 + 2*lm] = log2e * {rel_bias[h][i][kt*32+lm],
//                                               rel_bias[h][i][kt*32+16+lm]}
__global__ void cvt_rbt(const float* __restrict__ rel_bias, float* __restrict__ rbt) {
  int kt = blockIdx.x, ib = blockIdx.y, h = blockIdx.z;
  int lm = threadIdx.x & 15, ii = threadIdx.x >> 4;
  int i = ib * 16 + ii;
  float f0 = rel_bias[((size_t)h * MAXLEN + i) * MAXLEN + kt * 32 + lm] * 1.44269504f;
  float f1 = rel_bias[((size_t)h * MAXLEN + i) * MAXLEN + kt * 32 + 16 + lm] * 1.44269504f;
  float2 o = {f0, f1};
  *(float2*)&rbt[(((size_t)h * 15 + kt) * NS + i) * 32 + 2 * lm] = o;
}

// ---------------------------------------------------------------- qk_gemm
__global__ __launch_bounds__(256)
void qk_gemm(const ushort_t* __restrict__ xb,
             const ushort_t* __restrict__ wqT, const ushort_t* __restrict__ wkT,
             const float* __restrict__ bq, const float* __restrict__ bk,
             ushort_t* __restrict__ qb, ushort_t* __restrict__ kb) {
  __shared__ __align__(16) ushort_t sA[128 * 64];
  __shared__ __align__(16) ushort_t sB[128 * 64];
  const int tid = threadIdx.x;
  const int wid = tid >> 6, lane = tid & 63;
  const int lm = lane & 15, quad = lane >> 4;
  const int wr = wid >> 1, wc = wid & 1;
  const int row0 = blockIdx.x * 128;
  const int col0 = blockIdx.y * 128;
  const int z = blockIdx.z;
  const ushort_t* Bt = (z == 0) ? wqT : wkT;
  const float* bias = (z == 0) ? bq : bk;

  floatx4 zero4 = {0.f, 0.f, 0.f, 0.f};
  floatx4 acc[4][4];
#pragma unroll
  for (int i = 0; i < 4; ++i)
#pragma unroll
    for (int j = 0; j < 4; ++j) acc[i][j] = zero4;

  for (int k0 = 0; k0 < ND; k0 += 64) {
#pragma unroll
    for (int c = 0; c < 4; ++c) {
      int li = c * 256 + tid;
      int row = li >> 3, kc = li & 7;
      int kcs = kc ^ (row & 7);
      GLOAD_LDS16(xb + (row0 + row) * ND + k0 + kcs * 8, sA + (c * 256 + wid * 64) * 8);
      GLOAD_LDS16(Bt + (col0 + row) * ND + k0 + kcs * 8, sB + (c * 256 + wid * 64) * 8);
    }
    __syncthreads();
#pragma unroll
    for (int h2 = 0; h2 < 2; ++h2) {
      short8 a[4], b[4];
#pragma unroll
      for (int i = 0; i < 4; ++i) {
        int row = wr * 64 + i * 16 + lm;
        a[i] = *(const short8*)&sA[row * 64 + (((h2 << 2) | quad) ^ (lm & 7)) * 8];
      }
#pragma unroll
      for (int j = 0; j < 4; ++j) {
        int row = wc * 64 + j * 16 + lm;
        b[j] = *(const short8*)&sB[row * 64 + (((h2 << 2) | quad) ^ (lm & 7)) * 8];
      }
#pragma unroll
      for (int i = 0; i < 4; ++i)
#pragma unroll
        for (int j = 0; j < 4; ++j)
          acc[i][j] = __builtin_amdgcn_mfma_f32_16x16x32_bf16(a[i], b[j], acc[i][j], 0, 0, 0);
    }
    __syncthreads();
  }

  float bsv[4];
#pragma unroll
  for (int j = 0; j < 4; ++j) bsv[j] = bias[col0 + wc * 64 + j * 16 + lm];

#pragma unroll
  for (int i = 0; i < 4; ++i)
#pragma unroll
    for (int j = 0; j < 4; ++j)
#pragma unroll
      for (int r = 0; r < 4; ++r) {
        int m = row0 + wr * 64 + i * 16 + quad * 4 + r;
        int n = col0 + wc * 64 + j * 16 + lm;
        float val = acc[i][j][r] + bsv[j];
        int bb = m / NS, s = m - bb * NS;
        int h = n >> 6, d = n & 63;
        ushort_t o = f2bf(val);
        if (z == 0) qb[((bb * NH + h) * NS + s) * NDK + d] = o;
        else        kb[((bb * NH + h) * NS + s) * NDK + d] = o;
      }
}

// ---------------------------------------------------------------- v_gemm
__global__ __launch_bounds__(256)
void v_gemm(const ushort_t* __restrict__ xb, const ushort_t* __restrict__ wvT,
            const float* __restrict__ bv, ushort_t* __restrict__ vtil) {
  __shared__ __align__(16) ushort_t sA[128 * 64];
  __shared__ __align__(16) ushort_t sB[128 * 64];
  const int tid = threadIdx.x;
  const int wid = tid >> 6, lane = tid & 63;
  const int lm = lane & 15, quad = lane >> 4;
  const int wr = wid >> 1, wc = wid & 1;
  const int row0 = blockIdx.x * 128;  // dd
  const int col0 = blockIdx.y * 128;  // s
  const int b = blockIdx.z;
  const ushort_t* xbb = xb + (size_t)b * NS * ND;

  floatx4 zero4 = {0.f, 0.f, 0.f, 0.f};
  floatx4 acc[4][4];
#pragma unroll
  for (int i = 0; i < 4; ++i)
#pragma unroll
    for (int j = 0; j < 4; ++j) acc[i][j] = zero4;

  for (int k0 = 0; k0 < ND; k0 += 64) {
#pragma unroll
    for (int c = 0; c < 4; ++c) {
      int li = c * 256 + tid;
      int row = li >> 3, kc = li & 7;
      int kcs = kc ^ (row & 7);
      GLOAD_LDS16(wvT + (row0 + row) * ND + k0 + kcs * 8, sA + (c * 256 + wid * 64) * 8);
      int srow = min(col0 + row, NS - 1);
      GLOAD_LDS16(xbb + srow * ND + k0 + kcs * 8, sB + (c * 256 + wid * 64) * 8);
    }
    __syncthreads();
#pragma unroll
    for (int h2 = 0; h2 < 2; ++h2) {
      short8 a[4], b2[4];
#pragma unroll
      for (int i = 0; i < 4; ++i) {
        int row = wr * 64 + i * 16 + lm;
        a[i] = *(const short8*)&sA[row * 64 + (((h2 << 2) | quad) ^ (lm & 7)) * 8];
      }
#pragma unroll
      for (int j = 0; j < 4; ++j) {
        int row = wc * 64 + j * 16 + lm;
        b2[j] = *(const short8*)&sB[row * 64 + (((h2 << 2) | quad) ^ (lm & 7)) * 8];
      }
#pragma unroll
      for (int i = 0; i < 4; ++i)
#pragma unroll
        for (int j = 0; j < 4; ++j)
          acc[i][j] = __builtin_amdgcn_mfma_f32_16x16x32_bf16(a[i], b2[j], acc[i][j], 0, 0, 0);
    }
    __syncthreads();
  }

#pragma unroll
  for (int i = 0; i < 4; ++i)
#pragma unroll
    for (int r = 0; r < 4; ++r) {
      int m = row0 + wr * 64 + i * 16 + quad * 4 + r;  // dd = h*64 + d
      float bias = bv[m];
#pragma unroll
      for (int j = 0; j < 4; ++j) {
        int n = col0 + wc * 64 + j * 16 + lm;  // s
        if (n < NS) {
          size_t idx = (((size_t)b * NH + (m >> 6)) * 15 + (n >> 5)) * 2048 +
                       (m & 63) * 32 + (n & 31);
          vtil[idx] = f2bf(acc[i][j][r] + bias);
        }
      }
    }
}

// ---------------------------------------------------------------- flash_attn
// grid (256 bh, 4). wave w handles 32-row tile t = 14 - (y*4 + wid); no
// barriers, no max-tracking. Straight loop, loads at top (no reg-dbuf).
// Diagonal tile masked separately. cst = log2(lsum) [b][i][h].
__global__ __launch_bounds__(256)
void flash_attn(const ushort_t* __restrict__ qb, const ushort_t* __restrict__ kb,
                const ushort_t* __restrict__ vtil, const float* __restrict__ rbt,
                ushort_t* __restrict__ ctxb, float* __restrict__ cst) {
  const int bh = blockIdx.x;
  const int b = bh >> 3, h = bh & 7;
  const int tid = threadIdx.x;
  const int wid = tid >> 6, lane = tid & 63;
  const int lm = lane & 15, quad = lane >> 4;

  __shared__ __align__(16) ushort_t sP[4][32 * PSTR];

  const int t = 14 - (blockIdx.y * 4 + wid);  // longest tiles dispatched first
  if (t < 0) return;
  const int nkt = t + 1;

  const ushort_t* qh = qb + (size_t)bh * NS * NDK;
  const ushort_t* kh = kb + (size_t)bh * NS * NDK;
  const ushort_t* vb = vtil + (size_t)bh * 15 * 2048;
  const float* rb = rbt + (size_t)h * 15 * NS * 32;

  short8 aq[2][2];
#pragma unroll
  for (int g = 0; g < 2; ++g) {
    aq[g][0] = *(const short8*)&qh[(t * 32 + g * 16 + lm) * NDK + quad * 8];
    aq[g][1] = *(const short8*)&qh[(t * 32 + g * 16 + lm) * NDK + 32 + quad * 8];
  }

  float lsum[2][4];
  floatx4 O[2][4];
  floatx4 zero4 = {0.f, 0.f, 0.f, 0.f};
#pragma unroll
  for (int g = 0; g < 2; ++g) {
#pragma unroll
    for (int r = 0; r < 4; ++r) lsum[g][r] = 0.f;
#pragma unroll
    for (int jd = 0; jd < 4; ++jd) O[g][jd] = zero4;
  }

  for (int kt = 0; kt < nkt; ++kt) {
    const int kvA = kt * 32 + lm;
    const int kvB = kvA + 16;
    short8 bkA0 = *(const short8*)&kh[kvA * NDK + quad * 8];
    short8 bkA1 = *(const short8*)&kh[kvA * NDK + 32 + quad * 8];
    short8 bkB0 = *(const short8*)&kh[kvB * NDK + quad * 8];
    short8 bkB1 = *(const short8*)&kh[kvB * NDK + 32 + quad * 8];
    short8 bv2[4];
#pragma unroll
    for (int jd = 0; jd < 4; ++jd)
      bv2[jd] = *(const short8*)&vb[kt * 2048 + (jd * 16 + lm) * 32 + quad * 8];
    float2 bb[2][4];
#pragma unroll
    for (int g = 0; g < 2; ++g)
#pragma unroll
      for (int r = 0; r < 4; ++r) {
        int i = t * 32 + g * 16 + quad * 4 + r;
        bb[g][r] = *(const float2*)&rb[((size_t)kt * NS + i) * 32 + 2 * lm];
      }

    floatx4 sA[2], sB[2];
    __builtin_amdgcn_s_setprio(1);
#pragma unroll
    for (int g = 0; g < 2; ++g) {
      floatx4 s = zero4;
      s = __builtin_amdgcn_mfma_f32_16x16x32_bf16(aq[g][0], bkA0, s, 0, 0, 0);
      s = __builtin_amdgcn_mfma_f32_16x16x32_bf16(aq[g][1], bkA1, s, 0, 0, 0);
      sA[g] = s;
      s = zero4;
      s = __builtin_amdgcn_mfma_f32_16x16x32_bf16(aq[g][0], bkB0, s, 0, 0, 0);
      s = __builtin_amdgcn_mfma_f32_16x16x32_bf16(aq[g][1], bkB1, s, 0, 0, 0);
      sB[g] = s;
    }
    __builtin_amdgcn_s_setprio(0);

    if (kt < t) {  // off-diagonal: no causal mask needed
#pragma unroll
      for (int g = 0; g < 2; ++g)
#pragma unroll
        for (int r = 0; r < 4; ++r) {
          float p0 = __builtin_amdgcn_exp2f(fmaf(sA[g][r], SCL, bb[g][r].x));
          float p1 = __builtin_amdgcn_exp2f(fmaf(sB[g][r], SCL, bb[g][r].y));
          lsum[g][r] += p0 + p1;
          unsigned pk;
          asm("v_cvt_pk_bf16_f32 %0, %1, %2" : "=v"(pk) : "v"(p0), "v"(p1));
          sP[wid][(g * 16 + quad * 4 + r) * PSTR + lm] = (ushort_t)(pk & 0xffffu);
          sP[wid][(g * 16 + quad * 4 + r) * PSTR + 16 + lm] = (ushort_t)(pk >> 16);
        }
    } else {  // diagonal tile: mask j > i
#pragma unroll
      for (int g = 0; g < 2; ++g)
#pragma unroll
        for (int r = 0; r < 4; ++r) {
          int i = t * 32 + g * 16 + quad * 4 + r;
          float p0 = __builtin_amdgcn_exp2f(fmaf(sA[g][r], SCL, bb[g][r].x));
          float p1 = __builtin_amdgcn_exp2f(fmaf(sB[g][r], SCL, bb[g][r].y));
          if (kvA > i) p0 = 0.f;
          if (kvB > i) p1 = 0.f;
          lsum[g][r] += p0 + p1;
          unsigned pk;
          asm("v_cvt_pk_bf16_f32 %0, %1, %2" : "=v"(pk) : "v"(p0), "v"(p1));
          sP[wid][(g * 16 + quad * 4 + r) * PSTR + lm] = (ushort_t)(pk & 0xffffu);
          sP[wid][(g * 16 + quad * 4 + r) * PSTR + 16 + lm] = (ushort_t)(pk >> 16);
        }
    }

    __builtin_amdgcn_s_setprio(1);
#pragma unroll
    for (int g = 0; g < 2; ++g) {
      short8 ap = *(const short8*)&sP[wid][(g * 16 + lm) * PSTR + quad * 8];
#pragma unroll
      for (int jd = 0; jd < 4; ++jd)
        O[g][jd] = __builtin_amdgcn_mfma_f32_16x16x32_bf16(ap, bv2[jd], O[g][jd], 0, 0, 0);
    }
    __builtin_amdgcn_s_setprio(0);
  }

#pragma unroll
  for (int off = 1; off < 16; off <<= 1)
#pragma unroll
    for (int g = 0; g < 2; ++g)
#pragma unroll
      for (int r = 0; r < 4; ++r) lsum[g][r] += __shfl_xor(lsum[g][r], off, 64);

#pragma unroll
  for (int g = 0; g < 2; ++g) {
    float rinv[4];
#pragma unroll
    for (int r = 0; r < 4; ++r) rinv[r] = 1.f / lsum[g][r];
#pragma unroll
    for (int jd = 0; jd < 4; ++jd)
#pragma unroll
      for (int r = 0; r < 4; ++r) {
        int i = t * 32 + g * 16 + quad * 4 + r;
        ctxb[((size_t)b * NS + i) * ND + h * NDK + jd * 16 + lm] =
            f2bf(O[g][jd][r] * rinv[r]);
      }
    if (lm == 0) {
#pragma unroll
      for (int r = 0; r < 4; ++r) {
        int i = t * 32 + g * 16 + quad * 4 + r;
        cst[((size_t)b * NS + i) * NH + h] = __log2f(lsum[g][r]);
      }
    }
  }
}

// ---------------------------------------------------------------- attn_mean_k2
// Recompute S per (i64,j64) tile. K staged in LDS (double-buffered, 18KB).
// Bias loaded per-jj (transient scalars) from paired prescaled rbt;
// normalization fused into exponent: p = exp2(s*SCL + b' - c2).
// __launch_bounds__(256,4) caps VGPR at 128 -> 4 blocks/CU.
__global__ __launch_bounds__(256, 4)
void attn_mean_k2(const ushort_t* __restrict__ qb, const ushort_t* __restrict__ kb,
                  const float* __restrict__ rbt, const float* __restrict__ cst,
                  float* __restrict__ am) {
  const int b = blockIdx.x;
  const int tile = blockIdx.y;
  const int it = tile >> 3, jt = tile & 7;
  const int tid = threadIdx.x;

  if (jt > it) {  // strictly-masked tile: exact zeros
    int r = tid >> 2;
    int i = it * 64 + r;
    if (i < NS) {
      float4 z = {0.f, 0.f, 0.f, 0.f};
#pragma unroll
      for (int cc = 0; cc < 4; ++cc) {
        int j = jt * 64 + (tid & 3) * 16 + cc * 4;
        if (j < NS) *(float4*)&am[((size_t)b * NS + i) * NS + j] = z;
      }
    }
    return;
  }

  __shared__ __align__(16) ushort_t sK[2][64 * KSTRIDE];

  const int wid = tid >> 6, lane = tid & 63;
  const int lm = lane & 15, quad = lane >> 4;
  const int i0 = it * 64 + wid * 16;
  const bool active = (i0 < NS);
  const int j0t = jt * 64;
  const int iq = min(i0 + lm, NS - 1);

  int irow[4], ic[4];
#pragma unroll
  for (int r = 0; r < 4; ++r) {
    irow[r] = i0 + quad * 4 + r;
    ic[r] = min(irow[r], NS - 1);
  }
  const int kt2g0 = j0t >> 5;
  const int kt2g1 = min(kt2g0 + 1, 14);

  const int krow0 = tid >> 3, koff = (tid & 7) * 8;
  const int kr0 = min(j0t + krow0, NS - 1);
  const int kr1 = min(j0t + krow0 + 32, NS - 1);

  uint4 kreg[2];
  short8 qa0, qa1, qn0, qn1;

  {
    const ushort_t* kh = kb + (size_t)(b * NH) * NS * NDK;
    kreg[0] = *(const uint4*)&kh[kr0 * NDK + koff];
    kreg[1] = *(const uint4*)&kh[kr1 * NDK + koff];
    const ushort_t* qh = qb + (size_t)(b * NH) * NS * NDK;
    qa0 = *(const short8*)&qh[iq * NDK + quad * 8];
    qa1 = *(const short8*)&qh[iq * NDK + 32 + quad * 8];
    *(uint4*)&sK[0][krow0 * KSTRIDE + koff] = kreg[0];
    *(uint4*)&sK[0][(krow0 + 32) * KSTRIDE + koff] = kreg[1];
  }
  __syncthreads();

  floatx4 zero4 = {0.f, 0.f, 0.f, 0.f};
  floatx4 acc[4];
#pragma unroll
  for (int jj = 0; jj < 4; ++jj) acc[jj] = zero4;

#pragma unroll
  for (int h = 0; h < NH; ++h) {
    const int buf = h & 1;
    if (h < NH - 1) {
      const ushort_t* kh = kb + (size_t)(b * NH + h + 1) * NS * NDK;
      kreg[0] = *(const uint4*)&kh[kr0 * NDK + koff];
      kreg[1] = *(const uint4*)&kh[kr1 * NDK + koff];
      const ushort_t* qh = qb + (size_t)(b * NH + h + 1) * NS * NDK;
      qn0 = *(const short8*)&qh[iq * NDK + quad * 8];
      qn1 = *(const short8*)&qh[iq * NDK + 32 + quad * 8];
    }

    float c2[4];
#pragma unroll
    for (int r = 0; r < 4; ++r)
      c2[r] = cst[((size_t)b * NS + ic[r]) * NH + h];

#pragma unroll
    for (int jj = 0; jj < 4; ++jj) {
      // transient per-jj bias loads (issued before MFMAs that hide them)
      const int g2 = (jj < 2) ? kt2g0 : kt2g1;
      const int sel = jj & 1;
      float bsel[4];
#pragma unroll
      for (int r = 0; r < 4; ++r)
        bsel[r] = rbt[(((size_t)h * 15 + g2) * NS + ic[r]) * 32 + 2 * lm + sel];

      short8 bk0 = *(const short8*)&sK[buf][(jj * 16 + lm) * KSTRIDE + quad * 8];
      short8 bk1 = *(const short8*)&sK[buf][(jj * 16 + lm) * KSTRIDE + 32 + quad * 8];
      floatx4 s = zero4;
      __builtin_amdgcn_s_setprio(1);
      s = __builtin_amdgcn_mfma_f32_16x16x32_bf16(qa0, bk0, s, 0, 0, 0);
      s = __builtin_amdgcn_mfma_f32_16x16x32_bf16(qa1, bk1, s, 0, 0, 0);
      __builtin_amdgcn_s_setprio(0);
      int j = j0t + jj * 16 + lm;
#pragma unroll
      for (int r = 0; r < 4; ++r) {
        float p = __builtin_amdgcn_exp2f(fmaf(s[r], SCL, bsel[r] - c2[r]));
        if (j > irow[r]) p = 0.f;
        acc[jj][r] += p;
      }
    }

    if (h < NH - 1) {
      *(uint4*)&sK[buf ^ 1][krow0 * KSTRIDE + koff] = kreg[0];
      *(uint4*)&sK[buf ^ 1][(krow0 + 32) * KSTRIDE + koff] = kreg[1];
      qa0 = qn0; qa1 = qn1;
    }
    __syncthreads();
  }

  if (active) {
#pragma unroll
    for (int jj = 0; jj < 4; ++jj) {
      int j = j0t + jj * 16 + lm;
      if (j < NS) {
#pragma unroll
        for (int r = 0; r < 4; ++r)
          am[((size_t)b * NS + irow[r]) * NS + j] = acc[jj][r] * 0.125f;
      }
    }
  }
}

// ---------------------------------------------------------------- out_gemm
__global__ __launch_bounds__(256)
void out_gemm(const ushort_t* __restrict__ ctxb, const ushort_t* __restrict__ woT,
              const float* __restrict__ bo, float* __restrict__ out) {
  __shared__ __align__(16) ushort_t sA[128 * 64];
  __shared__ __align__(16) ushort_t sB[128 * 64];
  const int tid = threadIdx.x;
  const int wid = tid >> 6, lane = tid & 63;
  const int lm = lane & 15, quad = lane >> 4;
  const int wr = wid >> 1, wc = wid & 1;
  const int row0 = blockIdx.x * 128;
  const int col0 = blockIdx.y * 128;

  floatx4 zero4 = {0.f, 0.f, 0.f, 0.f};
  floatx4 acc[4][4];
#pragma unroll
  for (int i = 0; i < 4; ++i)
#pragma unroll
    for (int j = 0; j < 4; ++j) acc[i][j] = zero4;

  for (int k0 = 0; k0 < ND; k0 += 64) {
#pragma unroll
    for (int c = 0; c < 4; ++c) {
      int li = c * 256 + tid;
      int row = li >> 3, kc = li & 7;
      int kcs = kc ^ (row & 7);
      GLOAD_LDS16(ctxb + (row0 + row) * ND + k0 + kcs * 8, sA + (c * 256 + wid * 64) * 8);
      GLOAD_LDS16(woT + (col0 + row) * ND + k0 + kcs * 8, sB + (c * 256 + wid * 64) * 8);
    }
    __syncthreads();
#pragma unroll
    for (int h2 = 0; h2 < 2; ++h2) {
      short8 a[4], b[4];
#pragma unroll
      for (int i = 0; i < 4; ++i) {
        int row = wr * 64 + i * 16 + lm;
        a[i] = *(const short8*)&sA[row * 64 + (((h2 << 2) | quad) ^ (lm & 7)) * 8];
      }
#pragma unroll
      for (int j = 0; j < 4; ++j) {
        int row = wc * 64 + j * 16 + lm;
        b[j] = *(const short8*)&sB[row * 64 + (((h2 << 2) | quad) ^ (lm & 7)) * 8];
      }
#pragma unroll
      for (int i = 0; i < 4; ++i)
#pragma unroll
        for (int j = 0; j < 4; ++j)
          acc[i][j] = __builtin_amdgcn_mfma_f32_16x16x32_bf16(a[i], b[j], acc[i][j], 0, 0, 0);
    }
    __syncthreads();
  }

  float bsv[4];
#pragma unroll
  for (int j = 0; j < 4; ++j) bsv[j] = bo[col0 + wc * 64 + j * 16 + lm];

#pragma unroll
  for (int i = 0; i < 4; ++i)
#pragma unroll
    for (int j = 0; j < 4; ++j)
#pragma unroll
      for (int r = 0; r < 4; ++r) {
        int m = row0 + wr * 64 + i * 16 + quad * 4 + r;
        int n = col0 + wc * 64 + j * 16 + lm;
        out[m * ND + n] = acc[i][j][r] + bsv[j];
      }
}

// ---------------------------------------------------------------- launch
extern "C" void kernel_launch(void* const* d_in, const int* in_sizes, int n_in,
                              void* d_out, int out_size, void* d_ws, size_t ws_size,
                              hipStream_t stream) {
  const float* x  = (const float*)d_in[0];
  const float* wq = (const float*)d_in[1];
  const float* bq = (const float*)d_in[2];
  const float* wk = (const float*)d_in[3];
  const float* bk = (const float*)d_in[4];
  const float* wv = (const float*)d_in[5];
  const float* bv = (const float*)d_in[6];
  const float* wo = (const float*)d_in[7];
  const float* bo = (const float*)d_in[8];
  const float* rel_bias = (const float*)d_in[9];

  char* w = (char*)d_ws;
  ushort_t* xb  = (ushort_t*)w;                       // 15,728,640 B
  ushort_t* wqT = (ushort_t*)(w + 15728640);          // 4 x 524,288 B
  ushort_t* wkT = wqT + 262144;
  ushort_t* wvT = wkT + 262144;
  ushort_t* woT = wvT + 262144;
  ushort_t* qb  = (ushort_t*)(w + 15728640 + 4 * 524288);
  ushort_t* kb  = qb + 7864320;
  ushort_t* vtil = kb + 7864320;                      // tiled V
  ushort_t* ctxb = vtil + 7864320;
  float* cstat = (float*)(w + 80740352);              // log2(lsum) [b][i][h]
  // rbt (14,745,600 B) aliases xb — xb is dead after qk_gemm + v_gemm
  float* rbt = (float*)w;

  float* out0 = (float*)d_out;        // [32,480,512]
  float* attn_mean = out0 + 7864320;  // [32,480,480]

  cvt_x<<<dim3(7680), dim3(256), 0, stream>>>(x, xb);
  cvt_w<<<dim3(16, 16, 4), dim3(256), 0, stream>>>(wq, wk, wv, wo, wqT, wkT, wvT, woT);
  qk_gemm<<<dim3(120, 4, 2), dim3(256), 0, stream>>>(xb, wqT, wkT, bq, bk, qb, kb);
  v_gemm<<<dim3(4, 4, 32), dim3(256), 0, stream>>>(xb, wvT, bv, vtil);
  cvt_rbt<<<dim3(15, 30, 8), dim3(256), 0, stream>>>(rel_bias, rbt);
  flash_attn<<<dim3(256, 4), dim3(256), 0, stream>>>(qb, kb, vtil, rbt, ctxb, cstat);
  attn_mean_k2<<<dim3(32, 64), dim3(256), 0, stream>>>(qb, kb, rbt, cstat, attn_mean);
  out_gemm<<<dim3(120, 4), dim3(256), 0, stream>>>(ctxb, woT, bo, out0);
}

// Round 7
// 260.875 us; speedup vs baseline: 1.3035x; 1.3035x over previous
//
#include <hip/hip_runtime.h>
#include <hip/hip_bf16.h>

// B=32, S=480, D=512, H=8, dk=64. Outputs: out[32,480,512] fp32,
// attn_mean[32,480,480] fp32, concatenated in d_out.
//
// Pipeline (bf16 MFMA 16x16x32):
//  1. cvt_x      : x fp32 -> bf16
//  2. cvt_w      : w* fp32 [K][N] -> bf16 [N][K]
//  3. qk_gemm    : q/k -> [B,H,S,dk] bf16 (BK=64, XOR-swizzled LDS chunks)
//  4. v_gemm     : transposed gemm -> V TILED: vtil[bh][kt][d][32] (4KB/kt tile)
//  5. cvt_rbt    : rel_bias*log2e -> paired-tiled rbt[h][kt][i][{lm, 16+lm}]
//  6. flash_attn : 32 q-rows/wave, no barriers, no max-tracking (|s|<~3);
//                  straight loop (NO lambdas/reg-dbuf — spills to scratch),
//                  exp2-native prescaled bias, diagonal-only masking,
//                  cvt_pk_bf16 pack, setprio. cst = log2(lsum) [b][i][h].
//  7. attn_mean_k2: recompute S per (i64,j64) tile; K LDS-staged (dbuf 18KB),
//                  bias per-jj TRANSIENT loads, h-loop NOT unrolled
//                  (unroll-8 stretched liveness to 184 VGPR; forcing
//                  launch_bounds(256,4) spilled to 213MB scratch — both bad).
//                  Normalization fused into exponent (exp2(s*SCL+b'-c2)).
//  8. out_gemm   : ctx @ woT + bo -> fp32 (BK=64, swizzled)

typedef unsigned short ushort_t;
typedef __attribute__((ext_vector_type(8))) short short8;
typedef __attribute__((ext_vector_type(4))) float floatx4;

#define NB 32
#define NS 480
#define ND 512
#define NH 8
#define NDK 64
#define MAXLEN 500
#define KSTRIDE 72
#define PSTR 36   // sP row stride (ushorts): b128 frag reads <=2-way bank alias
#define SCL 0.18033688f  // 0.125 * log2(e)

__device__ __forceinline__ ushort_t f2bf(float f) {
  union { float f; unsigned u; } v; v.f = f;
  unsigned r = v.u + 0x7FFFu + ((v.u >> 16) & 1u);
  return (ushort_t)(r >> 16);
}

#define GLOAD_LDS16(g, l)                                                      \
  __builtin_amdgcn_global_load_lds(                                            \
      (const __attribute__((address_space(1))) void*)(g),                      \
      (__attribute__((address_space(3))) void*)(l), 16, 0, 0)

// ---------------------------------------------------------------- cvt_x
__global__ void cvt_x(const float* __restrict__ x, ushort_t* __restrict__ xb) {
  int idx = blockIdx.x * 256 + threadIdx.x;
  float4 v = ((const float4*)x)[idx];
  ushort4 o;
  o.x = f2bf(v.x); o.y = f2bf(v.y); o.z = f2bf(v.z); o.w = f2bf(v.w);
  ((ushort4*)xb)[idx] = o;
}

// ---------------------------------------------------------------- cvt_w
__global__ void cvt_w(const float* __restrict__ wq, const float* __restrict__ wk,
                      const float* __restrict__ wv, const float* __restrict__ wo,
                      ushort_t* __restrict__ wqT, ushort_t* __restrict__ wkT,
                      ushort_t* __restrict__ wvT, ushort_t* __restrict__ woT) {
  __shared__ float t[32][33];
  int z = blockIdx.z;
  const float* w = (z == 0) ? wq : (z == 1) ? wk : (z == 2) ? wv : wo;
  ushort_t* wT = (z == 0) ? wqT : (z == 1) ? wkT : (z == 2) ? wvT : woT;
  int k0 = blockIdx.x * 32, n0 = blockIdx.y * 32;
  int tx = threadIdx.x & 31, ty = threadIdx.x >> 5;
#pragma unroll
  for (int yy = 0; yy < 4; ++yy)
    t[ty + yy * 8][tx] = w[(k0 + ty + yy * 8) * ND + n0 + tx];
  __syncthreads();
#pragma unroll
  for (int yy = 0; yy < 4; ++yy)
    wT[(n0 + ty + yy * 8) * ND + k0 + tx] = f2bf(t[tx][ty + yy * 8]);
}

// ---------------------------------------------------------------- cvt_rbt
// rbt[((h*15+kt)*480 + i)*32 + 2*lm] = log2e * {rel_bias[h][i][kt*32+lm],
//                                               rel_bias[h][i][kt*32+16+lm]}
__global__ void cvt_rbt(const float* __restrict__ rel_bias, float* __restrict__ rbt) {
  int kt = blockIdx.x, ib = blockIdx.y, h = blockIdx.z;
  int lm = threadIdx.x & 15, ii = threadIdx.x >> 4;
  int i = ib * 16 + ii;
  float f0 = rel_bias[((size_t)h * MAXLEN + i) * MAXLEN + kt * 32 + lm] * 1.44269504f;
  float f1 = rel_bias[((size_t)h * MAXLEN + i) * MAXLEN + kt * 32 + 16 + lm] * 1.44269504f;
  float2 o = {f0, f1};
  *(float2*)&rbt[(((size_t)h * 15 + kt) * NS + i) * 32 + 2 * lm] = o;
}

// ---------------------------------------------------------------- qk_gemm
__global__ __launch_bounds__(256)
void qk_gemm(const ushort_t* __restrict__ xb,
             const ushort_t* __restrict__ wqT, const ushort_t* __restrict__ wkT,
             const float* __restrict__ bq, const float* __restrict__ bk,
             ushort_t* __restrict__ qb, ushort_t* __restrict__ kb) {
  __shared__ __align__(16) ushort_t sA[128 * 64];
  __shared__ __align__(16) ushort_t sB[128 * 64];
  const int tid = threadIdx.x;
  const int wid = tid >> 6, lane = tid & 63;
  const int lm = lane & 15, quad = lane >> 4;
  const int wr = wid >> 1, wc = wid & 1;
  const int row0 = blockIdx.x * 128;
  const int col0 = blockIdx.y * 128;
  const int z = blockIdx.z;
  const ushort_t* Bt = (z == 0) ? wqT : wkT;
  const float* bias = (z == 0) ? bq : bk;

  floatx4 zero4 = {0.f, 0.f, 0.f, 0.f};
  floatx4 acc[4][4];
#pragma unroll
  for (int i = 0; i < 4; ++i)
#pragma unroll
    for (int j = 0; j < 4; ++j) acc[i][j] = zero4;

  for (int k0 = 0; k0 < ND; k0 += 64) {
#pragma unroll
    for (int c = 0; c < 4; ++c) {
      int li = c * 256 + tid;
      int row = li >> 3, kc = li & 7;
      int kcs = kc ^ (row & 7);
      GLOAD_LDS16(xb + (row0 + row) * ND + k0 + kcs * 8, sA + (c * 256 + wid * 64) * 8);
      GLOAD_LDS16(Bt + (col0 + row) * ND + k0 + kcs * 8, sB + (c * 256 + wid * 64) * 8);
    }
    __syncthreads();
#pragma unroll
    for (int h2 = 0; h2 < 2; ++h2) {
      short8 a[4], b[4];
#pragma unroll
      for (int i = 0; i < 4; ++i) {
        int row = wr * 64 + i * 16 + lm;
        a[i] = *(const short8*)&sA[row * 64 + (((h2 << 2) | quad) ^ (lm & 7)) * 8];
      }
#pragma unroll
      for (int j = 0; j < 4; ++j) {
        int row = wc * 64 + j * 16 + lm;
        b[j] = *(const short8*)&sB[row * 64 + (((h2 << 2) | quad) ^ (lm & 7)) * 8];
      }
#pragma unroll
      for (int i = 0; i < 4; ++i)
#pragma unroll
        for (int j = 0; j < 4; ++j)
          acc[i][j] = __builtin_amdgcn_mfma_f32_16x16x32_bf16(a[i], b[j], acc[i][j], 0, 0, 0);
    }
    __syncthreads();
  }

  float bsv[4];
#pragma unroll
  for (int j = 0; j < 4; ++j) bsv[j] = bias[col0 + wc * 64 + j * 16 + lm];

#pragma unroll
  for (int i = 0; i < 4; ++i)
#pragma unroll
    for (int j = 0; j < 4; ++j)
#pragma unroll
      for (int r = 0; r < 4; ++r) {
        int m = row0 + wr * 64 + i * 16 + quad * 4 + r;
        int n = col0 + wc * 64 + j * 16 + lm;
        float val = acc[i][j][r] + bsv[j];
        int bb = m / NS, s = m - bb * NS;
        int h = n >> 6, d = n & 63;
        ushort_t o = f2bf(val);
        if (z == 0) qb[((bb * NH + h) * NS + s) * NDK + d] = o;
        else        kb[((bb * NH + h) * NS + s) * NDK + d] = o;
      }
}

// ---------------------------------------------------------------- v_gemm
__global__ __launch_bounds__(256)
void v_gemm(const ushort_t* __restrict__ xb, const ushort_t* __restrict__ wvT,
            const float* __restrict__ bv, ushort_t* __restrict__ vtil) {
  __shared__ __align__(16) ushort_t sA[128 * 64];
  __shared__ __align__(16) ushort_t sB[128 * 64];
  const int tid = threadIdx.x;
  const int wid = tid >> 6, lane = tid & 63;
  const int lm = lane & 15, quad = lane >> 4;
  const int wr = wid >> 1, wc = wid & 1;
  const int row0 = blockIdx.x * 128;  // dd
  const int col0 = blockIdx.y * 128;  // s
  const int b = blockIdx.z;
  const ushort_t* xbb = xb + (size_t)b * NS * ND;

  floatx4 zero4 = {0.f, 0.f, 0.f, 0.f};
  floatx4 acc[4][4];
#pragma unroll
  for (int i = 0; i < 4; ++i)
#pragma unroll
    for (int j = 0; j < 4; ++j) acc[i][j] = zero4;

  for (int k0 = 0; k0 < ND; k0 += 64) {
#pragma unroll
    for (int c = 0; c < 4; ++c) {
      int li = c * 256 + tid;
      int row = li >> 3, kc = li & 7;
      int kcs = kc ^ (row & 7);
      GLOAD_LDS16(wvT + (row0 + row) * ND + k0 + kcs * 8, sA + (c * 256 + wid * 64) * 8);
      int srow = min(col0 + row, NS - 1);
      GLOAD_LDS16(xbb + srow * ND + k0 + kcs * 8, sB + (c * 256 + wid * 64) * 8);
    }
    __syncthreads();
#pragma unroll
    for (int h2 = 0; h2 < 2; ++h2) {
      short8 a[4], b2[4];
#pragma unroll
      for (int i = 0; i < 4; ++i) {
        int row = wr * 64 + i * 16 + lm;
        a[i] = *(const short8*)&sA[row * 64 + (((h2 << 2) | quad) ^ (lm & 7)) * 8];
      }
#pragma unroll
      for (int j = 0; j < 4; ++j) {
        int row = wc * 64 + j * 16 + lm;
        b2[j] = *(const short8*)&sB[row * 64 + (((h2 << 2) | quad) ^ (lm & 7)) * 8];
      }
#pragma unroll
      for (int i = 0; i < 4; ++i)
#pragma unroll
        for (int j = 0; j < 4; ++j)
          acc[i][j] = __builtin_amdgcn_mfma_f32_16x16x32_bf16(a[i], b2[j], acc[i][j], 0, 0, 0);
    }
    __syncthreads();
  }

#pragma unroll
  for (int i = 0; i < 4; ++i)
#pragma unroll
    for (int r = 0; r < 4; ++r) {
      int m = row0 + wr * 64 + i * 16 + quad * 4 + r;  // dd = h*64 + d
      float bias = bv[m];
#pragma unroll
      for (int j = 0; j < 4; ++j) {
        int n = col0 + wc * 64 + j * 16 + lm;  // s
        if (n < NS) {
          size_t idx = (((size_t)b * NH + (m >> 6)) * 15 + (n >> 5)) * 2048 +
                       (m & 63) * 32 + (n & 31);
          vtil[idx] = f2bf(acc[i][j][r] + bias);
        }
      }
    }
}

// ---------------------------------------------------------------- flash_attn
// grid (256 bh, 4). wave w handles 32-row tile t = 14 - (y*4 + wid); no
// barriers, no max-tracking. Straight loop, loads at top (no reg-dbuf).
// Diagonal tile masked separately. cst = log2(lsum) [b][i][h].
__global__ __launch_bounds__(256)
void flash_attn(const ushort_t* __restrict__ qb, const ushort_t* __restrict__ kb,
                const ushort_t* __restrict__ vtil, const float* __restrict__ rbt,
                ushort_t* __restrict__ ctxb, float* __restrict__ cst) {
  const int bh = blockIdx.x;
  const int b = bh >> 3, h = bh & 7;
  const int tid = threadIdx.x;
  const int wid = tid >> 6, lane = tid & 63;
  const int lm = lane & 15, quad = lane >> 4;

  __shared__ __align__(16) ushort_t sP[4][32 * PSTR];

  const int t = 14 - (blockIdx.y * 4 + wid);  // longest tiles dispatched first
  if (t < 0) return;
  const int nkt = t + 1;

  const ushort_t* qh = qb + (size_t)bh * NS * NDK;
  const ushort_t* kh = kb + (size_t)bh * NS * NDK;
  const ushort_t* vb = vtil + (size_t)bh * 15 * 2048;
  const float* rb = rbt + (size_t)h * 15 * NS * 32;

  short8 aq[2][2];
#pragma unroll
  for (int g = 0; g < 2; ++g) {
    aq[g][0] = *(const short8*)&qh[(t * 32 + g * 16 + lm) * NDK + quad * 8];
    aq[g][1] = *(const short8*)&qh[(t * 32 + g * 16 + lm) * NDK + 32 + quad * 8];
  }

  float lsum[2][4];
  floatx4 O[2][4];
  floatx4 zero4 = {0.f, 0.f, 0.f, 0.f};
#pragma unroll
  for (int g = 0; g < 2; ++g) {
#pragma unroll
    for (int r = 0; r < 4; ++r) lsum[g][r] = 0.f;
#pragma unroll
    for (int jd = 0; jd < 4; ++jd) O[g][jd] = zero4;
  }

  for (int kt = 0; kt < nkt; ++kt) {
    const int kvA = kt * 32 + lm;
    const int kvB = kvA + 16;
    short8 bkA0 = *(const short8*)&kh[kvA * NDK + quad * 8];
    short8 bkA1 = *(const short8*)&kh[kvA * NDK + 32 + quad * 8];
    short8 bkB0 = *(const short8*)&kh[kvB * NDK + quad * 8];
    short8 bkB1 = *(const short8*)&kh[kvB * NDK + 32 + quad * 8];
    short8 bv2[4];
#pragma unroll
    for (int jd = 0; jd < 4; ++jd)
      bv2[jd] = *(const short8*)&vb[kt * 2048 + (jd * 16 + lm) * 32 + quad * 8];
    float2 bb[2][4];
#pragma unroll
    for (int g = 0; g < 2; ++g)
#pragma unroll
      for (int r = 0; r < 4; ++r) {
        int i = t * 32 + g * 16 + quad * 4 + r;
        bb[g][r] = *(const float2*)&rb[((size_t)kt * NS + i) * 32 + 2 * lm];
      }

    floatx4 sA[2], sB[2];
    __builtin_amdgcn_s_setprio(1);
#pragma unroll
    for (int g = 0; g < 2; ++g) {
      floatx4 s = zero4;
      s = __builtin_amdgcn_mfma_f32_16x16x32_bf16(aq[g][0], bkA0, s, 0, 0, 0);
      s = __builtin_amdgcn_mfma_f32_16x16x32_bf16(aq[g][1], bkA1, s, 0, 0, 0);
      sA[g] = s;
      s = zero4;
      s = __builtin_amdgcn_mfma_f32_16x16x32_bf16(aq[g][0], bkB0, s, 0, 0, 0);
      s = __builtin_amdgcn_mfma_f32_16x16x32_bf16(aq[g][1], bkB1, s, 0, 0, 0);
      sB[g] = s;
    }
    __builtin_amdgcn_s_setprio(0);

    if (kt < t) {  // off-diagonal: no causal mask needed
#pragma unroll
      for (int g = 0; g < 2; ++g)
#pragma unroll
        for (int r = 0; r < 4; ++r) {
          float p0 = __builtin_amdgcn_exp2f(fmaf(sA[g][r], SCL, bb[g][r].x));
          float p1 = __builtin_amdgcn_exp2f(fmaf(sB[g][r], SCL, bb[g][r].y));
          lsum[g][r] += p0 + p1;
          unsigned pk;
          asm("v_cvt_pk_bf16_f32 %0, %1, %2" : "=v"(pk) : "v"(p0), "v"(p1));
          sP[wid][(g * 16 + quad * 4 + r) * PSTR + lm] = (ushort_t)(pk & 0xffffu);
          sP[wid][(g * 16 + quad * 4 + r) * PSTR + 16 + lm] = (ushort_t)(pk >> 16);
        }
    } else {  // diagonal tile: mask j > i
#pragma unroll
      for (int g = 0; g < 2; ++g)
#pragma unroll
        for (int r = 0; r < 4; ++r) {
          int i = t * 32 + g * 16 + quad * 4 + r;
          float p0 = __builtin_amdgcn_exp2f(fmaf(sA[g][r], SCL, bb[g][r].x));
          float p1 = __builtin_amdgcn_exp2f(fmaf(sB[g][r], SCL, bb[g][r].y));
          if (kvA > i) p0 = 0.f;
          if (kvB > i) p1 = 0.f;
          lsum[g][r] += p0 + p1;
          unsigned pk;
          asm("v_cvt_pk_bf16_f32 %0, %1, %2" : "=v"(pk) : "v"(p0), "v"(p1));
          sP[wid][(g * 16 + quad * 4 + r) * PSTR + lm] = (ushort_t)(pk & 0xffffu);
          sP[wid][(g * 16 + quad * 4 + r) * PSTR + 16 + lm] = (ushort_t)(pk >> 16);
        }
    }

    __builtin_amdgcn_s_setprio(1);
#pragma unroll
    for (int g = 0; g < 2; ++g) {
      short8 ap = *(const short8*)&sP[wid][(g * 16 + lm) * PSTR + quad * 8];
#pragma unroll
      for (int jd = 0; jd < 4; ++jd)
        O[g][jd] = __builtin_amdgcn_mfma_f32_16x16x32_bf16(ap, bv2[jd], O[g][jd], 0, 0, 0);
    }
    __builtin_amdgcn_s_setprio(0);
  }

#pragma unroll
  for (int off = 1; off < 16; off <<= 1)
#pragma unroll
    for (int g = 0; g < 2; ++g)
#pragma unroll
      for (int r = 0; r < 4; ++r) lsum[g][r] += __shfl_xor(lsum[g][r], off, 64);

#pragma unroll
  for (int g = 0; g < 2; ++g) {
    float rinv[4];
#pragma unroll
    for (int r = 0; r < 4; ++r) rinv[r] = 1.f / lsum[g][r];
#pragma unroll
    for (int jd = 0; jd < 4; ++jd)
#pragma unroll
      for (int r = 0; r < 4; ++r) {
        int i = t * 32 + g * 16 + quad * 4 + r;
        ctxb[((size_t)b * NS + i) * ND + h * NDK + jd * 16 + lm] =
            f2bf(O[g][jd][r] * rinv[r]);
      }
    if (lm == 0) {
#pragma unroll
      for (int r = 0; r < 4; ++r) {
        int i = t * 32 + g * 16 + quad * 4 + r;
        cst[((size_t)b * NS + i) * NH + h] = __log2f(lsum[g][r]);
      }
    }
  }
}

// ---------------------------------------------------------------- attn_mean_k2
// Recompute S per (i64,j64) tile. K staged in LDS (double-buffered, 18KB).
// Bias loaded per-jj (transient) from paired prescaled rbt; normalization
// fused into exponent: p = exp2(s*SCL + b' - c2). h-loop NOT unrolled to
// keep VGPR liveness low (unroll-8 -> 184 VGPR -> 2 waves/SIMD).
__global__ __launch_bounds__(256)
void attn_mean_k2(const ushort_t* __restrict__ qb, const ushort_t* __restrict__ kb,
                  const float* __restrict__ rbt, const float* __restrict__ cst,
                  float* __restrict__ am) {
  const int b = blockIdx.x;
  const int tile = blockIdx.y;
  const int it = tile >> 3, jt = tile & 7;
  const int tid = threadIdx.x;

  if (jt > it) {  // strictly-masked tile: exact zeros
    int r = tid >> 2;
    int i = it * 64 + r;
    if (i < NS) {
      float4 z = {0.f, 0.f, 0.f, 0.f};
#pragma unroll
      for (int cc = 0; cc < 4; ++cc) {
        int j = jt * 64 + (tid & 3) * 16 + cc * 4;
        if (j < NS) *(float4*)&am[((size_t)b * NS + i) * NS + j] = z;
      }
    }
    return;
  }

  __shared__ __align__(16) ushort_t sK[2][64 * KSTRIDE];

  const int wid = tid >> 6, lane = tid & 63;
  const int lm = lane & 15, quad = lane >> 4;
  const int i0 = it * 64 + wid * 16;
  const bool active = (i0 < NS);
  const int j0t = jt * 64;
  const int iq = min(i0 + lm, NS - 1);

  int irow[4], ic[4];
#pragma unroll
  for (int r = 0; r < 4; ++r) {
    irow[r] = i0 + quad * 4 + r;
    ic[r] = min(irow[r], NS - 1);
  }
  const int kt2g0 = j0t >> 5;
  const int kt2g1 = min(kt2g0 + 1, 14);

  const int krow0 = tid >> 3, koff = (tid & 7) * 8;
  const int kr0 = min(j0t + krow0, NS - 1);
  const int kr1 = min(j0t + krow0 + 32, NS - 1);

  uint4 kreg[2];
  short8 qa0, qa1, qn0, qn1;

  {
    const ushort_t* kh = kb + (size_t)(b * NH) * NS * NDK;
    kreg[0] = *(const uint4*)&kh[kr0 * NDK + koff];
    kreg[1] = *(const uint4*)&kh[kr1 * NDK + koff];
    const ushort_t* qh = qb + (size_t)(b * NH) * NS * NDK;
    qa0 = *(const short8*)&qh[iq * NDK + quad * 8];
    qa1 = *(const short8*)&qh[iq * NDK + 32 + quad * 8];
    *(uint4*)&sK[0][krow0 * KSTRIDE + koff] = kreg[0];
    *(uint4*)&sK[0][(krow0 + 32) * KSTRIDE + koff] = kreg[1];
  }
  __syncthreads();

  floatx4 zero4 = {0.f, 0.f, 0.f, 0.f};
  floatx4 acc[4];
#pragma unroll
  for (int jj = 0; jj < 4; ++jj) acc[jj] = zero4;

#pragma unroll 1
  for (int h = 0; h < NH; ++h) {
    const int buf = h & 1;
    if (h < NH - 1) {
      const ushort_t* kh = kb + (size_t)(b * NH + h + 1) * NS * NDK;
      kreg[0] = *(const uint4*)&kh[kr0 * NDK + koff];
      kreg[1] = *(const uint4*)&kh[kr1 * NDK + koff];
      const ushort_t* qh = qb + (size_t)(b * NH + h + 1) * NS * NDK;
      qn0 = *(const short8*)&qh[iq * NDK + quad * 8];
      qn1 = *(const short8*)&qh[iq * NDK + 32 + quad * 8];
    }

    float c2[4];
#pragma unroll
    for (int r = 0; r < 4; ++r)
      c2[r] = cst[((size_t)b * NS + ic[r]) * NH + h];

#pragma unroll
    for (int jj = 0; jj < 4; ++jj) {
      // transient per-jj bias loads (issued before MFMAs that hide them)
      const int g2 = (jj < 2) ? kt2g0 : kt2g1;
      const int sel = jj & 1;
      float bsel[4];
#pragma unroll
      for (int r = 0; r < 4; ++r)
        bsel[r] = rbt[(((size_t)h * 15 + g2) * NS + ic[r]) * 32 + 2 * lm + sel];

      short8 bk0 = *(const short8*)&sK[buf][(jj * 16 + lm) * KSTRIDE + quad * 8];
      short8 bk1 = *(const short8*)&sK[buf][(jj * 16 + lm) * KSTRIDE + 32 + quad * 8];
      floatx4 s = zero4;
      __builtin_amdgcn_s_setprio(1);
      s = __builtin_amdgcn_mfma_f32_16x16x32_bf16(qa0, bk0, s, 0, 0, 0);
      s = __builtin_amdgcn_mfma_f32_16x16x32_bf16(qa1, bk1, s, 0, 0, 0);
      __builtin_amdgcn_s_setprio(0);
      int j = j0t + jj * 16 + lm;
#pragma unroll
      for (int r = 0; r < 4; ++r) {
        float p = __builtin_amdgcn_exp2f(fmaf(s[r], SCL, bsel[r] - c2[r]));
        if (j > irow[r]) p = 0.f;
        acc[jj][r] += p;
      }
    }

    if (h < NH - 1) {
      *(uint4*)&sK[buf ^ 1][krow0 * KSTRIDE + koff] = kreg[0];
      *(uint4*)&sK[buf ^ 1][(krow0 + 32) * KSTRIDE + koff] = kreg[1];
      qa0 = qn0; qa1 = qn1;
    }
    __syncthreads();
  }

  if (active) {
#pragma unroll
    for (int jj = 0; jj < 4; ++jj) {
      int j = j0t + jj * 16 + lm;
      if (j < NS) {
#pragma unroll
        for (int r = 0; r < 4; ++r)
          am[((size_t)b * NS + irow[r]) * NS + j] = acc[jj][r] * 0.125f;
      }
    }
  }
}

// ---------------------------------------------------------------- out_gemm
__global__ __launch_bounds__(256)
void out_gemm(const ushort_t* __restrict__ ctxb, const ushort_t* __restrict__ woT,
              const float* __restrict__ bo, float* __restrict__ out) {
  __shared__ __align__(16) ushort_t sA[128 * 64];
  __shared__ __align__(16) ushort_t sB[128 * 64];
  const int tid = threadIdx.x;
  const int wid = tid >> 6, lane = tid & 63;
  const int lm = lane & 15, quad = lane >> 4;
  const int wr = wid >> 1, wc = wid & 1;
  const int row0 = blockIdx.x * 128;
  const int col0 = blockIdx.y * 128;

  floatx4 zero4 = {0.f, 0.f, 0.f, 0.f};
  floatx4 acc[4][4];
#pragma unroll
  for (int i = 0; i < 4; ++i)
#pragma unroll
    for (int j = 0; j < 4; ++j) acc[i][j] = zero4;

  for (int k0 = 0; k0 < ND; k0 += 64) {
#pragma unroll
    for (int c = 0; c < 4; ++c) {
      int li = c * 256 + tid;
      int row = li >> 3, kc = li & 7;
      int kcs = kc ^ (row & 7);
      GLOAD_LDS16(ctxb + (row0 + row) * ND + k0 + kcs * 8, sA + (c * 256 + wid * 64) * 8);
      GLOAD_LDS16(woT + (col0 + row) * ND + k0 + kcs * 8, sB + (c * 256 + wid * 64) * 8);
    }
    __syncthreads();
#pragma unroll
    for (int h2 = 0; h2 < 2; ++h2) {
      short8 a[4], b[4];
#pragma unroll
      for (int i = 0; i < 4; ++i) {
        int row = wr * 64 + i * 16 + lm;
        a[i] = *(const short8*)&sA[row * 64 + (((h2 << 2) | quad) ^ (lm & 7)) * 8];
      }
#pragma unroll
      for (int j = 0; j < 4; ++j) {
        int row = wc * 64 + j * 16 + lm;
        b[j] = *(const short8*)&sB[row * 64 + (((h2 << 2) | quad) ^ (lm & 7)) * 8];
      }
#pragma unroll
      for (int i = 0; i < 4; ++i)
#pragma unroll
        for (int j = 0; j < 4; ++j)
          acc[i][j] = __builtin_amdgcn_mfma_f32_16x16x32_bf16(a[i], b[j], acc[i][j], 0, 0, 0);
    }
    __syncthreads();
  }

  float bsv[4];
#pragma unroll
  for (int j = 0; j < 4; ++j) bsv[j] = bo[col0 + wc * 64 + j * 16 + lm];

#pragma unroll
  for (int i = 0; i < 4; ++i)
#pragma unroll
    for (int j = 0; j < 4; ++j)
#pragma unroll
      for (int r = 0; r < 4; ++r) {
        int m = row0 + wr * 64 + i * 16 + quad * 4 + r;
        int n = col0 + wc * 64 + j * 16 + lm;
        out[m * ND + n] = acc[i][j][r] + bsv[j];
      }
}

// ---------------------------------------------------------------- launch
extern "C" void kernel_launch(void* const* d_in, const int* in_sizes, int n_in,
                              void* d_out, int out_size, void* d_ws, size_t ws_size,
                              hipStream_t stream) {
  const float* x  = (const float*)d_in[0];
  const float* wq = (const float*)d_in[1];
  const float* bq = (const float*)d_in[2];
  const float* wk = (const float*)d_in[3];
  const float* bk = (const float*)d_in[4];
  const float* wv = (const float*)d_in[5];
  const float* bv = (const float*)d_in[6];
  const float* wo = (const float*)d_in[7];
  const float* bo = (const float*)d_in[8];
  const float* rel_bias = (const float*)d_in[9];

  char* w = (char*)d_ws;
  ushort_t* xb  = (ushort_t*)w;                       // 15,728,640 B
  ushort_t* wqT = (ushort_t*)(w + 15728640);          // 4 x 524,288 B
  ushort_t* wkT = wqT + 262144;
  ushort_t* wvT = wkT + 262144;
  ushort_t* woT = wvT + 262144;
  ushort_t* qb  = (ushort_t*)(w + 15728640 + 4 * 524288);
  ushort_t* kb  = qb + 7864320;
  ushort_t* vtil = kb + 7864320;                      // tiled V
  ushort_t* ctxb = vtil + 7864320;
  float* cstat = (float*)(w + 80740352);              // log2(lsum) [b][i][h]
  // rbt (14,745,600 B) aliases xb — xb is dead after qk_gemm + v_gemm
  float* rbt = (float*)w;

  float* out0 = (float*)d_out;        // [32,480,512]
  float* attn_mean = out0 + 7864320;  // [32,480,480]

  cvt_x<<<dim3(7680), dim3(256), 0, stream>>>(x, xb);
  cvt_w<<<dim3(16, 16, 4), dim3(256), 0, stream>>>(wq, wk, wv, wo, wqT, wkT, wvT, woT);
  qk_gemm<<<dim3(120, 4, 2), dim3(256), 0, stream>>>(xb, wqT, wkT, bq, bk, qb, kb);
  v_gemm<<<dim3(4, 4, 32), dim3(256), 0, stream>>>(xb, wvT, bv, vtil);
  cvt_rbt<<<dim3(15, 30, 8), dim3(256), 0, stream>>>(rel_bias, rbt);
  flash_attn<<<dim3(256, 4), dim3(256), 0, stream>>>(qb, kb, vtil, rbt, ctxb, cstat);
  attn_mean_k2<<<dim3(32, 64), dim3(256), 0, stream>>>(qb, kb, rbt, cstat, attn_mean);
  out_gemm<<<dim3(120, 4), dim3(256), 0, stream>>>(ctxb, woT, bo, out0);
}

// Round 8
// 230.948 us; speedup vs baseline: 1.4724x; 1.1296x over previous
//
#include <hip/hip_runtime.h>
#include <hip/hip_bf16.h>

// B=32, S=480, D=512, H=8, dk=64. Outputs: out[32,480,512] fp32,
// attn_mean[32,480,480] fp32, concatenated in d_out.
//
// Pipeline (bf16 MFMA 16x16x32):
//  1. cvt_x      : x fp32 -> bf16
//  2. cvt_w      : w* fp32 [K][N] -> bf16 [N][K]
//  3. qk_gemm    : q/k -> [B,H,S,dk] bf16 (BK=64, XOR-swizzled LDS chunks)
//  4. v_gemm     : transposed gemm -> V TILED: vtil[bh][kt][d][32] (4KB/kt tile)
//  5. cvt_rbt    : rel_bias*log2e -> paired-tiled rbt[h][kt][i][{lm, 16+lm}]
//  6. flash_attn : 32 q-rows/wave, no barriers, no max-tracking (|s|<~3);
//                  straight loop (NO lambdas/reg-dbuf — those spill to
//                  scratch, rounds 1-4), exp2-native prescaled bias,
//                  diagonal-only masking, cvt_pk_bf16 pack, setprio.
//                  Dumps P tiles fp16 (cvt_pkrtz) to pscr, COALESCED:
//                  uint4 slot (bh*120+tri(t)+kt)*128 + g*64 + lane
//                  (1024B contiguous per store instr). cst = 1/lsum [bh][i].
//  7. attn_mean_p: pure streaming mean: read pscr (8 heads) * rinv -> fp32.
//                  (recompute-mean abandoned: latency-bound at 45-52us across
//                  3 variants; VGPR cliff 184-nospill vs 64-spill)
//  8. out_gemm   : ctx @ woT + bo -> fp32 (BK=64, swizzled)

typedef unsigned short ushort_t;
typedef __attribute__((ext_vector_type(8))) short short8;
typedef __attribute__((ext_vector_type(4))) float floatx4;
typedef __attribute__((ext_vector_type(2))) __fp16 half2v;

#define NB 32
#define NS 480
#define ND 512
#define NH 8
#define NDK 64
#define MAXLEN 500
#define PSTR 36   // sP row stride (ushorts): b128 frag reads <=2-way bank alias
#define SCL 0.18033688f  // 0.125 * log2(e)

__device__ __forceinline__ ushort_t f2bf(float f) {
  union { float f; unsigned u; } v; v.f = f;
  unsigned r = v.u + 0x7FFFu + ((v.u >> 16) & 1u);
  return (ushort_t)(r >> 16);
}

#define GLOAD_LDS16(g, l)                                                      \
  __builtin_amdgcn_global_load_lds(                                            \
      (const __attribute__((address_space(1))) void*)(g),                      \
      (__attribute__((address_space(3))) void*)(l), 16, 0, 0)

// ---------------------------------------------------------------- cvt_x
__global__ void cvt_x(const float* __restrict__ x, ushort_t* __restrict__ xb) {
  int idx = blockIdx.x * 256 + threadIdx.x;
  float4 v = ((const float4*)x)[idx];
  ushort4 o;
  o.x = f2bf(v.x); o.y = f2bf(v.y); o.z = f2bf(v.z); o.w = f2bf(v.w);
  ((ushort4*)xb)[idx] = o;
}

// ---------------------------------------------------------------- cvt_w
__global__ void cvt_w(const float* __restrict__ wq, const float* __restrict__ wk,
                      const float* __restrict__ wv, const float* __restrict__ wo,
                      ushort_t* __restrict__ wqT, ushort_t* __restrict__ wkT,
                      ushort_t* __restrict__ wvT, ushort_t* __restrict__ woT) {
  __shared__ float t[32][33];
  int z = blockIdx.z;
  const float* w = (z == 0) ? wq : (z == 1) ? wk : (z == 2) ? wv : wo;
  ushort_t* wT = (z == 0) ? wqT : (z == 1) ? wkT : (z == 2) ? wvT : woT;
  int k0 = blockIdx.x * 32, n0 = blockIdx.y * 32;
  int tx = threadIdx.x & 31, ty = threadIdx.x >> 5;
#pragma unroll
  for (int yy = 0; yy < 4; ++yy)
    t[ty + yy * 8][tx] = w[(k0 + ty + yy * 8) * ND + n0 + tx];
  __syncthreads();
#pragma unroll
  for (int yy = 0; yy < 4; ++yy)
    wT[(n0 + ty + yy * 8) * ND + k0 + tx] = f2bf(t[tx][ty + yy * 8]);
}

// ---------------------------------------------------------------- cvt_rbt
// rbt[((h*15+kt)*480 + i)*32 + 2*lm] = log2e * {rel_bias[h][i][kt*32+lm],
//                                               rel_bias[h][i][kt*32+16+lm]}
__global__ void cvt_rbt(const float* __restrict__ rel_bias, float* __restrict__ rbt) {
  int kt = blockIdx.x, ib = blockIdx.y, h = blockIdx.z;
  int lm = threadIdx.x & 15, ii = threadIdx.x >> 4;
  int i = ib * 16 + ii;
  float f0 = rel_bias[((size_t)h * MAXLEN + i) * MAXLEN + kt * 32 + lm] * 1.44269504f;
  float f1 = rel_bias[((size_t)h * MAXLEN + i) * MAXLEN + kt * 32 + 16 + lm] * 1.44269504f;
  float2 o = {f0, f1};
  *(float2*)&rbt[(((size_t)h * 15 + kt) * NS + i) * 32 + 2 * lm] = o;
}

// ---------------------------------------------------------------- qk_gemm
__global__ __launch_bounds__(256)
void qk_gemm(const ushort_t* __restrict__ xb,
             const ushort_t* __restrict__ wqT, const ushort_t* __restrict__ wkT,
             const float* __restrict__ bq, const float* __restrict__ bk,
             ushort_t* __restrict__ qb, ushort_t* __restrict__ kb) {
  __shared__ __align__(16) ushort_t sA[128 * 64];
  __shared__ __align__(16) ushort_t sB[128 * 64];
  const int tid = threadIdx.x;
  const int wid = tid >> 6, lane = tid & 63;
  const int lm = lane & 15, quad = lane >> 4;
  const int wr = wid >> 1, wc = wid & 1;
  const int row0 = blockIdx.x * 128;
  const int col0 = blockIdx.y * 128;
  const int z = blockIdx.z;
  const ushort_t* Bt = (z == 0) ? wqT : wkT;
  const float* bias = (z == 0) ? bq : bk;

  floatx4 zero4 = {0.f, 0.f, 0.f, 0.f};
  floatx4 acc[4][4];
#pragma unroll
  for (int i = 0; i < 4; ++i)
#pragma unroll
    for (int j = 0; j < 4; ++j) acc[i][j] = zero4;

  for (int k0 = 0; k0 < ND; k0 += 64) {
#pragma unroll
    for (int c = 0; c < 4; ++c) {
      int li = c * 256 + tid;
      int row = li >> 3, kc = li & 7;
      int kcs = kc ^ (row & 7);
      GLOAD_LDS16(xb + (row0 + row) * ND + k0 + kcs * 8, sA + (c * 256 + wid * 64) * 8);
      GLOAD_LDS16(Bt + (col0 + row) * ND + k0 + kcs * 8, sB + (c * 256 + wid * 64) * 8);
    }
    __syncthreads();
#pragma unroll
    for (int h2 = 0; h2 < 2; ++h2) {
      short8 a[4], b[4];
#pragma unroll
      for (int i = 0; i < 4; ++i) {
        int row = wr * 64 + i * 16 + lm;
        a[i] = *(const short8*)&sA[row * 64 + (((h2 << 2) | quad) ^ (lm & 7)) * 8];
      }
#pragma unroll
      for (int j = 0; j < 4; ++j) {
        int row = wc * 64 + j * 16 + lm;
        b[j] = *(const short8*)&sB[row * 64 + (((h2 << 2) | quad) ^ (lm & 7)) * 8];
      }
#pragma unroll
      for (int i = 0; i < 4; ++i)
#pragma unroll
        for (int j = 0; j < 4; ++j)
          acc[i][j] = __builtin_amdgcn_mfma_f32_16x16x32_bf16(a[i], b[j], acc[i][j], 0, 0, 0);
    }
    __syncthreads();
  }

  float bsv[4];
#pragma unroll
  for (int j = 0; j < 4; ++j) bsv[j] = bias[col0 + wc * 64 + j * 16 + lm];

#pragma unroll
  for (int i = 0; i < 4; ++i)
#pragma unroll
    for (int j = 0; j < 4; ++j)
#pragma unroll
      for (int r = 0; r < 4; ++r) {
        int m = row0 + wr * 64 + i * 16 + quad * 4 + r;
        int n = col0 + wc * 64 + j * 16 + lm;
        float val = acc[i][j][r] + bsv[j];
        int bb = m / NS, s = m - bb * NS;
        int h = n >> 6, d = n & 63;
        ushort_t o = f2bf(val);
        if (z == 0) qb[((bb * NH + h) * NS + s) * NDK + d] = o;
        else        kb[((bb * NH + h) * NS + s) * NDK + d] = o;
      }
}

// ---------------------------------------------------------------- v_gemm
__global__ __launch_bounds__(256)
void v_gemm(const ushort_t* __restrict__ xb, const ushort_t* __restrict__ wvT,
            const float* __restrict__ bv, ushort_t* __restrict__ vtil) {
  __shared__ __align__(16) ushort_t sA[128 * 64];
  __shared__ __align__(16) ushort_t sB[128 * 64];
  const int tid = threadIdx.x;
  const int wid = tid >> 6, lane = tid & 63;
  const int lm = lane & 15, quad = lane >> 4;
  const int wr = wid >> 1, wc = wid & 1;
  const int row0 = blockIdx.x * 128;  // dd
  const int col0 = blockIdx.y * 128;  // s
  const int b = blockIdx.z;
  const ushort_t* xbb = xb + (size_t)b * NS * ND;

  floatx4 zero4 = {0.f, 0.f, 0.f, 0.f};
  floatx4 acc[4][4];
#pragma unroll
  for (int i = 0; i < 4; ++i)
#pragma unroll
    for (int j = 0; j < 4; ++j) acc[i][j] = zero4;

  for (int k0 = 0; k0 < ND; k0 += 64) {
#pragma unroll
    for (int c = 0; c < 4; ++c) {
      int li = c * 256 + tid;
      int row = li >> 3, kc = li & 7;
      int kcs = kc ^ (row & 7);
      GLOAD_LDS16(wvT + (row0 + row) * ND + k0 + kcs * 8, sA + (c * 256 + wid * 64) * 8);
      int srow = min(col0 + row, NS - 1);
      GLOAD_LDS16(xbb + srow * ND + k0 + kcs * 8, sB + (c * 256 + wid * 64) * 8);
    }
    __syncthreads();
#pragma unroll
    for (int h2 = 0; h2 < 2; ++h2) {
      short8 a[4], b2[4];
#pragma unroll
      for (int i = 0; i < 4; ++i) {
        int row = wr * 64 + i * 16 + lm;
        a[i] = *(const short8*)&sA[row * 64 + (((h2 << 2) | quad) ^ (lm & 7)) * 8];
      }
#pragma unroll
      for (int j = 0; j < 4; ++j) {
        int row = wc * 64 + j * 16 + lm;
        b2[j] = *(const short8*)&sB[row * 64 + (((h2 << 2) | quad) ^ (lm & 7)) * 8];
      }
#pragma unroll
      for (int i = 0; i < 4; ++i)
#pragma unroll
        for (int j = 0; j < 4; ++j)
          acc[i][j] = __builtin_amdgcn_mfma_f32_16x16x32_bf16(a[i], b2[j], acc[i][j], 0, 0, 0);
    }
    __syncthreads();
  }

#pragma unroll
  for (int i = 0; i < 4; ++i)
#pragma unroll
    for (int r = 0; r < 4; ++r) {
      int m = row0 + wr * 64 + i * 16 + quad * 4 + r;  // dd = h*64 + d
      float bias = bv[m];
#pragma unroll
      for (int j = 0; j < 4; ++j) {
        int n = col0 + wc * 64 + j * 16 + lm;  // s
        if (n < NS) {
          size_t idx = (((size_t)b * NH + (m >> 6)) * 15 + (n >> 5)) * 2048 +
                       (m & 63) * 32 + (n & 31);
          vtil[idx] = f2bf(acc[i][j][r] + bias);
        }
      }
    }
}

// ---------------------------------------------------------------- flash_attn
// grid (256 bh, 4). wave w handles 32-row tile t = 14 - (y*4 + wid); no
// barriers, no max-tracking. Straight loop (no lambdas/reg-dbuf). Diagonal
// tile masked separately. P tiles dumped fp16 to pscr (coalesced uint4 slots
// (bh*120+tri(t)+kt)*128 + g*64 + lane). cst = 1/lsum, layout [bh][i].
__global__ __launch_bounds__(256)
void flash_attn(const ushort_t* __restrict__ qb, const ushort_t* __restrict__ kb,
                const ushort_t* __restrict__ vtil, const float* __restrict__ rbt,
                ushort_t* __restrict__ ctxb, float* __restrict__ cst,
                uint4* __restrict__ pscr) {
  const int bh = blockIdx.x;
  const int b = bh >> 3, h = bh & 7;
  const int tid = threadIdx.x;
  const int wid = tid >> 6, lane = tid & 63;
  const int lm = lane & 15, quad = lane >> 4;

  __shared__ __align__(16) ushort_t sP[4][32 * PSTR];

  const int t = 14 - (blockIdx.y * 4 + wid);  // longest tiles dispatched first
  if (t < 0) return;
  const int nkt = t + 1;

  const ushort_t* qh = qb + (size_t)bh * NS * NDK;
  const ushort_t* kh = kb + (size_t)bh * NS * NDK;
  const ushort_t* vb = vtil + (size_t)bh * 15 * 2048;
  const float* rb = rbt + (size_t)h * 15 * NS * 32;
  uint4* pp = pscr + ((size_t)(bh * 120 + (t * (t + 1)) / 2)) * 128 + lane;

  short8 aq[2][2];
#pragma unroll
  for (int g = 0; g < 2; ++g) {
    aq[g][0] = *(const short8*)&qh[(t * 32 + g * 16 + lm) * NDK + quad * 8];
    aq[g][1] = *(const short8*)&qh[(t * 32 + g * 16 + lm) * NDK + 32 + quad * 8];
  }

  float lsum[2][4];
  floatx4 O[2][4];
  floatx4 zero4 = {0.f, 0.f, 0.f, 0.f};
#pragma unroll
  for (int g = 0; g < 2; ++g) {
#pragma unroll
    for (int r = 0; r < 4; ++r) lsum[g][r] = 0.f;
#pragma unroll
    for (int jd = 0; jd < 4; ++jd) O[g][jd] = zero4;
  }

  for (int kt = 0; kt < nkt; ++kt) {
    const int kvA = kt * 32 + lm;
    const int kvB = kvA + 16;
    short8 bkA0 = *(const short8*)&kh[kvA * NDK + quad * 8];
    short8 bkA1 = *(const short8*)&kh[kvA * NDK + 32 + quad * 8];
    short8 bkB0 = *(const short8*)&kh[kvB * NDK + quad * 8];
    short8 bkB1 = *(const short8*)&kh[kvB * NDK + 32 + quad * 8];
    short8 bv2[4];
#pragma unroll
    for (int jd = 0; jd < 4; ++jd)
      bv2[jd] = *(const short8*)&vb[kt * 2048 + (jd * 16 + lm) * 32 + quad * 8];
    float2 bb[2][4];
#pragma unroll
    for (int g = 0; g < 2; ++g)
#pragma unroll
      for (int r = 0; r < 4; ++r) {
        int i = t * 32 + g * 16 + quad * 4 + r;
        bb[g][r] = *(const float2*)&rb[((size_t)kt * NS + i) * 32 + 2 * lm];
      }

    floatx4 sA[2], sB[2];
    __builtin_amdgcn_s_setprio(1);
#pragma unroll
    for (int g = 0; g < 2; ++g) {
      floatx4 s = zero4;
      s = __builtin_amdgcn_mfma_f32_16x16x32_bf16(aq[g][0], bkA0, s, 0, 0, 0);
      s = __builtin_amdgcn_mfma_f32_16x16x32_bf16(aq[g][1], bkA1, s, 0, 0, 0);
      sA[g] = s;
      s = zero4;
      s = __builtin_amdgcn_mfma_f32_16x16x32_bf16(aq[g][0], bkB0, s, 0, 0, 0);
      s = __builtin_amdgcn_mfma_f32_16x16x32_bf16(aq[g][1], bkB1, s, 0, 0, 0);
      sB[g] = s;
    }
    __builtin_amdgcn_s_setprio(0);

    const bool diag = (kt == t);  // wave-uniform
#pragma unroll
    for (int g = 0; g < 2; ++g) {
      unsigned pw[4];
#pragma unroll
      for (int r = 0; r < 4; ++r) {
        float p0 = __builtin_amdgcn_exp2f(fmaf(sA[g][r], SCL, bb[g][r].x));
        float p1 = __builtin_amdgcn_exp2f(fmaf(sB[g][r], SCL, bb[g][r].y));
        if (diag) {
          int i = t * 32 + g * 16 + quad * 4 + r;
          if (kvA > i) p0 = 0.f;
          if (kvB > i) p1 = 0.f;
        }
        lsum[g][r] += p0 + p1;
        unsigned pk;
        asm("v_cvt_pk_bf16_f32 %0, %1, %2" : "=v"(pk) : "v"(p0), "v"(p1));
        sP[wid][(g * 16 + quad * 4 + r) * PSTR + lm] = (ushort_t)(pk & 0xffffu);
        sP[wid][(g * 16 + quad * 4 + r) * PSTR + 16 + lm] = (ushort_t)(pk >> 16);
        half2v hp = __builtin_amdgcn_cvt_pkrtz(p0, p1);
        pw[r] = *(unsigned*)&hp;
      }
      uint4 pq = {pw[0], pw[1], pw[2], pw[3]};
      pp[(size_t)kt * 128 + g * 64] = pq;  // fire-and-forget, 1KB/instr
    }

    __builtin_amdgcn_s_setprio(1);
#pragma unroll
    for (int g = 0; g < 2; ++g) {
      short8 ap = *(const short8*)&sP[wid][(g * 16 + lm) * PSTR + quad * 8];
#pragma unroll
      for (int jd = 0; jd < 4; ++jd)
        O[g][jd] = __builtin_amdgcn_mfma_f32_16x16x32_bf16(ap, bv2[jd], O[g][jd], 0, 0, 0);
    }
    __builtin_amdgcn_s_setprio(0);
  }

#pragma unroll
  for (int off = 1; off < 16; off <<= 1)
#pragma unroll
    for (int g = 0; g < 2; ++g)
#pragma unroll
      for (int r = 0; r < 4; ++r) lsum[g][r] += __shfl_xor(lsum[g][r], off, 64);

#pragma unroll
  for (int g = 0; g < 2; ++g) {
    float rinv[4];
#pragma unroll
    for (int r = 0; r < 4; ++r) rinv[r] = 1.f / lsum[g][r];
#pragma unroll
    for (int jd = 0; jd < 4; ++jd)
#pragma unroll
      for (int r = 0; r < 4; ++r) {
        int i = t * 32 + g * 16 + quad * 4 + r;
        ctxb[((size_t)b * NS + i) * ND + h * NDK + jd * 16 + lm] =
            f2bf(O[g][jd][r] * rinv[r]);
      }
    if (lm == 0) {
#pragma unroll
      for (int r = 0; r < 4; ++r) {
        int i = t * 32 + g * 16 + quad * 4 + r;
        cst[(size_t)bh * NS + i] = rinv[r];
      }
    }
  }
}

// ---------------------------------------------------------------- attn_mean_p
// Streaming mean over heads from the P scratch written by flash_attn.
// grid (32 b, 15 t, 15 kt), 1 wave/block. kt>t tiles: zero-fill.
__global__ __launch_bounds__(64)
void attn_mean_p(const uint4* __restrict__ pscr, const float* __restrict__ cst,
                 float* __restrict__ am) {
  const int b = blockIdx.x, t = blockIdx.y, kt = blockIdx.z;
  const int lane = threadIdx.x;
  const int lm = lane & 15, quad = lane >> 4;
  float* outp = am + ((size_t)b * NS + t * 32) * NS + (size_t)kt * 32;
  if (kt > t) {
#pragma unroll
    for (int g = 0; g < 2; ++g)
#pragma unroll
      for (int r = 0; r < 4; ++r) {
        int row = g * 16 + quad * 4 + r;
        outp[(size_t)row * NS + lm] = 0.f;
        outp[(size_t)row * NS + 16 + lm] = 0.f;
      }
    return;
  }
  const int m = (t * (t + 1)) / 2 + kt;
  float a0[2][4], a1[2][4];
#pragma unroll
  for (int g = 0; g < 2; ++g)
#pragma unroll
    for (int r = 0; r < 4; ++r) { a0[g][r] = 0.f; a1[g][r] = 0.f; }

#pragma unroll
  for (int h = 0; h < NH; ++h) {
    const uint4* pp = pscr + ((size_t)(b * NH + h) * 120 + m) * 128 + lane;
    uint4 q0 = pp[0];        // g=0: rows quad*4..+3 of 0..15, cols lm/16+lm
    uint4 q1 = pp[64];       // g=1
    unsigned pu[8] = {q0.x, q0.y, q0.z, q0.w, q1.x, q1.y, q1.z, q1.w};
    const float* cp = cst + (size_t)(b * NH + h) * NS + t * 32 + quad * 4;
    float4 rv0 = *(const float4*)cp;
    float4 rv1 = *(const float4*)(cp + 16);
    float rv[8] = {rv0.x, rv0.y, rv0.z, rv0.w, rv1.x, rv1.y, rv1.z, rv1.w};
#pragma unroll
    for (int g = 0; g < 2; ++g)
#pragma unroll
      for (int r = 0; r < 4; ++r) {
        half2v hp = *(half2v*)&pu[g * 4 + r];
        a0[g][r] = fmaf((float)hp.x, rv[g * 4 + r], a0[g][r]);
        a1[g][r] = fmaf((float)hp.y, rv[g * 4 + r], a1[g][r]);
      }
  }

#pragma unroll
  for (int g = 0; g < 2; ++g)
#pragma unroll
    for (int r = 0; r < 4; ++r) {
      int row = g * 16 + quad * 4 + r;
      outp[(size_t)row * NS + lm] = a0[g][r] * 0.125f;
      outp[(size_t)row * NS + 16 + lm] = a1[g][r] * 0.125f;
    }
}

// ---------------------------------------------------------------- out_gemm
__global__ __launch_bounds__(256)
void out_gemm(const ushort_t* __restrict__ ctxb, const ushort_t* __restrict__ woT,
              const float* __restrict__ bo, float* __restrict__ out) {
  __shared__ __align__(16) ushort_t sA[128 * 64];
  __shared__ __align__(16) ushort_t sB[128 * 64];
  const int tid = threadIdx.x;
  const int wid = tid >> 6, lane = tid & 63;
  const int lm = lane & 15, quad = lane >> 4;
  const int wr = wid >> 1, wc = wid & 1;
  const int row0 = blockIdx.x * 128;
  const int col0 = blockIdx.y * 128;

  floatx4 zero4 = {0.f, 0.f, 0.f, 0.f};
  floatx4 acc[4][4];
#pragma unroll
  for (int i = 0; i < 4; ++i)
#pragma unroll
    for (int j = 0; j < 4; ++j) acc[i][j] = zero4;

  for (int k0 = 0; k0 < ND; k0 += 64) {
#pragma unroll
    for (int c = 0; c < 4; ++c) {
      int li = c * 256 + tid;
      int row = li >> 3, kc = li & 7;
      int kcs = kc ^ (row & 7);
      GLOAD_LDS16(ctxb + (row0 + row) * ND + k0 + kcs * 8, sA + (c * 256 + wid * 64) * 8);
      GLOAD_LDS16(woT + (col0 + row) * ND + k0 + kcs * 8, sB + (c * 256 + wid * 64) * 8);
    }
    __syncthreads();
#pragma unroll
    for (int h2 = 0; h2 < 2; ++h2) {
      short8 a[4], b[4];
#pragma unroll
      for (int i = 0; i < 4; ++i) {
        int row = wr * 64 + i * 16 + lm;
        a[i] = *(const short8*)&sA[row * 64 + (((h2 << 2) | quad) ^ (lm & 7)) * 8];
      }
#pragma unroll
      for (int j = 0; j < 4; ++j) {
        int row = wc * 64 + j * 16 + lm;
        b[j] = *(const short8*)&sB[row * 64 + (((h2 << 2) | quad) ^ (lm & 7)) * 8];
      }
#pragma unroll
      for (int i = 0; i < 4; ++i)
#pragma unroll
        for (int j = 0; j < 4; ++j)
          acc[i][j] = __builtin_amdgcn_mfma_f32_16x16x32_bf16(a[i], b[j], acc[i][j], 0, 0, 0);
    }
    __syncthreads();
  }

  float bsv[4];
#pragma unroll
  for (int j = 0; j < 4; ++j) bsv[j] = bo[col0 + wc * 64 + j * 16 + lm];

#pragma unroll
  for (int i = 0; i < 4; ++i)
#pragma unroll
    for (int j = 0; j < 4; ++j)
#pragma unroll
      for (int r = 0; r < 4; ++r) {
        int m = row0 + wr * 64 + i * 16 + quad * 4 + r;
        int n = col0 + wc * 64 + j * 16 + lm;
        out[m * ND + n] = acc[i][j][r] + bsv[j];
      }
}

// ---------------------------------------------------------------- launch
extern "C" void kernel_launch(void* const* d_in, const int* in_sizes, int n_in,
                              void* d_out, int out_size, void* d_ws, size_t ws_size,
                              hipStream_t stream) {
  const float* x  = (const float*)d_in[0];
  const float* wq = (const float*)d_in[1];
  const float* bq = (const float*)d_in[2];
  const float* wk = (const float*)d_in[3];
  const float* bk = (const float*)d_in[4];
  const float* wv = (const float*)d_in[5];
  const float* bv = (const float*)d_in[6];
  const float* wo = (const float*)d_in[7];
  const float* bo = (const float*)d_in[8];
  const float* rel_bias = (const float*)d_in[9];

  char* w = (char*)d_ws;
  ushort_t* xb  = (ushort_t*)w;                       // 15,728,640 B
  ushort_t* wqT = (ushort_t*)(w + 15728640);          // 4 x 524,288 B
  ushort_t* wkT = wqT + 262144;
  ushort_t* wvT = wkT + 262144;
  ushort_t* woT = wvT + 262144;
  ushort_t* qb  = (ushort_t*)(w + 15728640 + 4 * 524288);
  ushort_t* kb  = qb + 7864320;
  ushort_t* vtil = kb + 7864320;                      // tiled V
  ushort_t* ctxb = vtil + 7864320;
  float* cstat = (float*)(w + 80740352);              // rinv [bh][i], 491,520 B
  uint4* pscr = (uint4*)(w + 81264640);               // P scratch, 62,914,560 B
  // rbt (14,745,600 B) aliases xb — xb is dead after qk_gemm + v_gemm
  float* rbt = (float*)w;

  float* out0 = (float*)d_out;        // [32,480,512]
  float* attn_mean = out0 + 7864320;  // [32,480,480]

  cvt_x<<<dim3(7680), dim3(256), 0, stream>>>(x, xb);
  cvt_w<<<dim3(16, 16, 4), dim3(256), 0, stream>>>(wq, wk, wv, wo, wqT, wkT, wvT, woT);
  qk_gemm<<<dim3(120, 4, 2), dim3(256), 0, stream>>>(xb, wqT, wkT, bq, bk, qb, kb);
  v_gemm<<<dim3(4, 4, 32), dim3(256), 0, stream>>>(xb, wvT, bv, vtil);
  cvt_rbt<<<dim3(15, 30, 8), dim3(256), 0, stream>>>(rel_bias, rbt);
  flash_attn<<<dim3(256, 4), dim3(256), 0, stream>>>(qb, kb, vtil, rbt, ctxb, cstat, pscr);
  attn_mean_p<<<dim3(32, 15, 15), dim3(64), 0, stream>>>(pscr, cstat, attn_mean);
  out_gemm<<<dim3(120, 4), dim3(256), 0, stream>>>(ctxb, woT, bo, out0);
}

// Round 9
// 226.430 us; speedup vs baseline: 1.5018x; 1.0200x over previous
//
#include <hip/hip_runtime.h>
#include <hip/hip_bf16.h>

// B=32, S=480, D=512, H=8, dk=64. Outputs: out[32,480,512] fp32,
// attn_mean[32,480,480] fp32, concatenated in d_out.
//
// Pipeline (bf16 MFMA 16x16x32), 6 launches:
//  1. cvt_xw     : x fp32->bf16 (blocks <7680) + w* transpose (blocks >=7680)
//  2. qkv_gemm   : z<2 -> q/k gemm (x<120), z==2 -> V tiled gemm (b=x>>2).
//                  Merged so qk and v blocks overlap (independent work).
//  3. cvt_rbt    : rel_bias*log2e -> paired rbt (MUST follow qkv: rbt aliases xb)
//  4. flash_attn : BALANCED PAIRING: slot s<7 -> tiles {s,13-s}, s==7 -> {14};
//                  every wave = exactly 15 kt-iterations (kills the t=14
//                  straggler tail that held occupancy at 15%). grid (256,2).
//                  Straight loop (no lambdas/reg-dbuf - spills), exp2-native,
//                  diag-only masking, cvt_pk, setprio. P tiles fp16 -> pscr
//                  coalesced; cst = 1/lsum [bh][i].
//  5. attn_mean_p: streaming mean: read pscr (8 heads) * rinv -> fp32.
//  6. out_gemm   : ctx @ woT + bo -> fp32

typedef unsigned short ushort_t;
typedef __attribute__((ext_vector_type(8))) short short8;
typedef __attribute__((ext_vector_type(4))) float floatx4;
typedef __attribute__((ext_vector_type(2))) __fp16 half2v;

#define NB 32
#define NS 480
#define ND 512
#define NH 8
#define NDK 64
#define MAXLEN 500
#define PSTR 36   // sP row stride (ushorts): b128 frag reads <=2-way bank alias
#define SCL 0.18033688f  // 0.125 * log2(e)

__device__ __forceinline__ ushort_t f2bf(float f) {
  union { float f; unsigned u; } v; v.f = f;
  unsigned r = v.u + 0x7FFFu + ((v.u >> 16) & 1u);
  return (ushort_t)(r >> 16);
}

#define GLOAD_LDS16(g, l)                                                      \
  __builtin_amdgcn_global_load_lds(                                            \
      (const __attribute__((address_space(1))) void*)(g),                      \
      (__attribute__((address_space(3))) void*)(l), 16, 0, 0)

// ---------------------------------------------------------------- cvt_xw
// blocks [0,7680): x fp32->bf16 vectorized. blocks [7680,8704): w transpose.
__global__ __launch_bounds__(256)
void cvt_xw(const float* __restrict__ x, const float* __restrict__ wq,
            const float* __restrict__ wk, const float* __restrict__ wv,
            const float* __restrict__ wo, ushort_t* __restrict__ xb,
            ushort_t* __restrict__ wqT, ushort_t* __restrict__ wkT,
            ushort_t* __restrict__ wvT, ushort_t* __restrict__ woT) {
  __shared__ float t[32][33];
  const int bid = blockIdx.x;
  if (bid < 7680) {
    int idx = bid * 256 + threadIdx.x;
    float4 v = ((const float4*)x)[idx];
    ushort4 o;
    o.x = f2bf(v.x); o.y = f2bf(v.y); o.z = f2bf(v.z); o.w = f2bf(v.w);
    ((ushort4*)xb)[idx] = o;
    return;
  }
  const int q = bid - 7680;
  const int z = q >> 8;
  const float* w = (z == 0) ? wq : (z == 1) ? wk : (z == 2) ? wv : wo;
  ushort_t* wT = (z == 0) ? wqT : (z == 1) ? wkT : (z == 2) ? wvT : woT;
  int k0 = (q & 15) * 32, n0 = ((q >> 4) & 15) * 32;
  int tx = threadIdx.x & 31, ty = threadIdx.x >> 5;
#pragma unroll
  for (int yy = 0; yy < 4; ++yy)
    t[ty + yy * 8][tx] = w[(k0 + ty + yy * 8) * ND + n0 + tx];
  __syncthreads();
#pragma unroll
  for (int yy = 0; yy < 4; ++yy)
    wT[(n0 + ty + yy * 8) * ND + k0 + tx] = f2bf(t[tx][ty + yy * 8]);
}

// ---------------------------------------------------------------- cvt_rbt
// rbt[((h*15+kt)*480 + i)*32 + 2*lm] = log2e * {rel_bias[h][i][kt*32+lm],
//                                               rel_bias[h][i][kt*32+16+lm]}
__global__ void cvt_rbt(const float* __restrict__ rel_bias, float* __restrict__ rbt) {
  int kt = blockIdx.x, ib = blockIdx.y, h = blockIdx.z;
  int lm = threadIdx.x & 15, ii = threadIdx.x >> 4;
  int i = ib * 16 + ii;
  float f0 = rel_bias[((size_t)h * MAXLEN + i) * MAXLEN + kt * 32 + lm] * 1.44269504f;
  float f1 = rel_bias[((size_t)h * MAXLEN + i) * MAXLEN + kt * 32 + 16 + lm] * 1.44269504f;
  float2 o = {f0, f1};
  *(float2*)&rbt[(((size_t)h * 15 + kt) * NS + i) * 32 + 2 * lm] = o;
}

// ---------------------------------------------------------------- qkv_gemm
// z in {0,1}: q/k gemm (blocks x<120 active; row over flattened B*S).
// z == 2   : V tiled gemm, b = x>>2, dd-tile = x&3, s-tile = y.
__global__ __launch_bounds__(256)
void qkv_gemm(const ushort_t* __restrict__ xb,
              const ushort_t* __restrict__ wqT, const ushort_t* __restrict__ wkT,
              const ushort_t* __restrict__ wvT,
              const float* __restrict__ bq, const float* __restrict__ bk,
              const float* __restrict__ bv,
              ushort_t* __restrict__ qb, ushort_t* __restrict__ kb,
              ushort_t* __restrict__ vtil) {
  __shared__ __align__(16) ushort_t sA[128 * 64];
  __shared__ __align__(16) ushort_t sB[128 * 64];
  const int tid = threadIdx.x;
  const int wid = tid >> 6, lane = tid & 63;
  const int lm = lane & 15, quad = lane >> 4;
  const int wr = wid >> 1, wc = wid & 1;
  const int z = blockIdx.z;

  floatx4 zero4 = {0.f, 0.f, 0.f, 0.f};
  floatx4 acc[4][4];
#pragma unroll
  for (int i = 0; i < 4; ++i)
#pragma unroll
    for (int j = 0; j < 4; ++j) acc[i][j] = zero4;

  if (z < 2) {
    if (blockIdx.x >= 120) return;
    const int row0 = blockIdx.x * 128;
    const int col0 = blockIdx.y * 128;
    const ushort_t* Bt = (z == 0) ? wqT : wkT;
    const float* bias = (z == 0) ? bq : bk;

    for (int k0 = 0; k0 < ND; k0 += 64) {
#pragma unroll
      for (int c = 0; c < 4; ++c) {
        int li = c * 256 + tid;
        int row = li >> 3, kc = li & 7;
        int kcs = kc ^ (row & 7);
        GLOAD_LDS16(xb + (row0 + row) * ND + k0 + kcs * 8, sA + (c * 256 + wid * 64) * 8);
        GLOAD_LDS16(Bt + (col0 + row) * ND + k0 + kcs * 8, sB + (c * 256 + wid * 64) * 8);
      }
      __syncthreads();
#pragma unroll
      for (int h2 = 0; h2 < 2; ++h2) {
        short8 a[4], b[4];
#pragma unroll
        for (int i = 0; i < 4; ++i) {
          int row = wr * 64 + i * 16 + lm;
          a[i] = *(const short8*)&sA[row * 64 + (((h2 << 2) | quad) ^ (lm & 7)) * 8];
        }
#pragma unroll
        for (int j = 0; j < 4; ++j) {
          int row = wc * 64 + j * 16 + lm;
          b[j] = *(const short8*)&sB[row * 64 + (((h2 << 2) | quad) ^ (lm & 7)) * 8];
        }
#pragma unroll
        for (int i = 0; i < 4; ++i)
#pragma unroll
          for (int j = 0; j < 4; ++j)
            acc[i][j] = __builtin_amdgcn_mfma_f32_16x16x32_bf16(a[i], b[j], acc[i][j], 0, 0, 0);
      }
      __syncthreads();
    }

    float bsv[4];
#pragma unroll
    for (int j = 0; j < 4; ++j) bsv[j] = bias[col0 + wc * 64 + j * 16 + lm];

#pragma unroll
    for (int i = 0; i < 4; ++i)
#pragma unroll
      for (int j = 0; j < 4; ++j)
#pragma unroll
        for (int r = 0; r < 4; ++r) {
          int m = row0 + wr * 64 + i * 16 + quad * 4 + r;
          int n = col0 + wc * 64 + j * 16 + lm;
          float val = acc[i][j][r] + bsv[j];
          int bb = m / NS, s = m - bb * NS;
          int h = n >> 6, d = n & 63;
          ushort_t o = f2bf(val);
          if (z == 0) qb[((bb * NH + h) * NS + s) * NDK + d] = o;
          else        kb[((bb * NH + h) * NS + s) * NDK + d] = o;
        }
  } else {
    const int b = blockIdx.x >> 2;
    const int row0 = (blockIdx.x & 3) * 128;  // dd
    const int col0 = blockIdx.y * 128;        // s
    const ushort_t* xbb = xb + (size_t)b * NS * ND;

    for (int k0 = 0; k0 < ND; k0 += 64) {
#pragma unroll
      for (int c = 0; c < 4; ++c) {
        int li = c * 256 + tid;
        int row = li >> 3, kc = li & 7;
        int kcs = kc ^ (row & 7);
        GLOAD_LDS16(wvT + (row0 + row) * ND + k0 + kcs * 8, sA + (c * 256 + wid * 64) * 8);
        int srow = min(col0 + row, NS - 1);
        GLOAD_LDS16(xbb + srow * ND + k0 + kcs * 8, sB + (c * 256 + wid * 64) * 8);
      }
      __syncthreads();
#pragma unroll
      for (int h2 = 0; h2 < 2; ++h2) {
        short8 a[4], b2[4];
#pragma unroll
        for (int i = 0; i < 4; ++i) {
          int row = wr * 64 + i * 16 + lm;
          a[i] = *(const short8*)&sA[row * 64 + (((h2 << 2) | quad) ^ (lm & 7)) * 8];
        }
#pragma unroll
        for (int j = 0; j < 4; ++j) {
          int row = wc * 64 + j * 16 + lm;
          b2[j] = *(const short8*)&sB[row * 64 + (((h2 << 2) | quad) ^ (lm & 7)) * 8];
        }
#pragma unroll
        for (int i = 0; i < 4; ++i)
#pragma unroll
          for (int j = 0; j < 4; ++j)
            acc[i][j] = __builtin_amdgcn_mfma_f32_16x16x32_bf16(a[i], b2[j], acc[i][j], 0, 0, 0);
      }
      __syncthreads();
    }

#pragma unroll
    for (int i = 0; i < 4; ++i)
#pragma unroll
      for (int r = 0; r < 4; ++r) {
        int m = row0 + wr * 64 + i * 16 + quad * 4 + r;  // dd = h*64 + d
        float bias = bv[m];
#pragma unroll
        for (int j = 0; j < 4; ++j) {
          int n = col0 + wc * 64 + j * 16 + lm;  // s
          if (n < NS) {
            size_t idx = (((size_t)b * NH + (m >> 6)) * 15 + (n >> 5)) * 2048 +
                         (m & 63) * 32 + (n & 31);
            vtil[idx] = f2bf(acc[i][j][r] + bias);
          }
        }
      }
  }
}

// ---------------------------------------------------------------- flash_attn
// grid (256 bh, 2). slot = y*4+wid in 0..7; slot<7 -> tiles {slot, 13-slot},
// slot==7 -> {14}: every wave runs exactly 15 kt-iterations (load-balanced).
// Straight loop (no lambdas/reg-dbuf). Diag tile masked. P tiles fp16 ->
// pscr coalesced uint4 slots (bh*120+tri(t)+kt)*128 + g*64 + lane.
// cst = 1/lsum, layout [bh][i].
__global__ __launch_bounds__(256)
void flash_attn(const ushort_t* __restrict__ qb, const ushort_t* __restrict__ kb,
                const ushort_t* __restrict__ vtil, const float* __restrict__ rbt,
                ushort_t* __restrict__ ctxb, float* __restrict__ cst,
                uint4* __restrict__ pscr) {
  const int bh = blockIdx.x;
  const int b = bh >> 3, h = bh & 7;
  const int tid = threadIdx.x;
  const int wid = tid >> 6, lane = tid & 63;
  const int lm = lane & 15, quad = lane >> 4;

  __shared__ __align__(16) ushort_t sP[4][32 * PSTR];

  const int slot = blockIdx.y * 4 + wid;  // 0..7
  const int tA = (slot == 7) ? 14 : slot;
  const int tB = (slot == 7) ? -1 : 13 - slot;

  const ushort_t* qh = qb + (size_t)bh * NS * NDK;
  const ushort_t* kh = kb + (size_t)bh * NS * NDK;
  const ushort_t* vb = vtil + (size_t)bh * 15 * 2048;
  const float* rb = rbt + (size_t)h * 15 * NS * 32;

#pragma unroll 1
  for (int ti = 0; ti < 2; ++ti) {
    const int t = (ti == 0) ? tA : tB;
    if (t < 0) break;
    const int nkt = t + 1;
    uint4* pp = pscr + ((size_t)(bh * 120 + (t * (t + 1)) / 2)) * 128 + lane;

    short8 aq[2][2];
#pragma unroll
    for (int g = 0; g < 2; ++g) {
      aq[g][0] = *(const short8*)&qh[(t * 32 + g * 16 + lm) * NDK + quad * 8];
      aq[g][1] = *(const short8*)&qh[(t * 32 + g * 16 + lm) * NDK + 32 + quad * 8];
    }

    float lsum[2][4];
    floatx4 O[2][4];
    floatx4 zero4 = {0.f, 0.f, 0.f, 0.f};
#pragma unroll
    for (int g = 0; g < 2; ++g) {
#pragma unroll
      for (int r = 0; r < 4; ++r) lsum[g][r] = 0.f;
#pragma unroll
      for (int jd = 0; jd < 4; ++jd) O[g][jd] = zero4;
    }

    for (int kt = 0; kt < nkt; ++kt) {
      const int kvA = kt * 32 + lm;
      const int kvB = kvA + 16;
      short8 bkA0 = *(const short8*)&kh[kvA * NDK + quad * 8];
      short8 bkA1 = *(const short8*)&kh[kvA * NDK + 32 + quad * 8];
      short8 bkB0 = *(const short8*)&kh[kvB * NDK + quad * 8];
      short8 bkB1 = *(const short8*)&kh[kvB * NDK + 32 + quad * 8];
      short8 bv2[4];
#pragma unroll
      for (int jd = 0; jd < 4; ++jd)
        bv2[jd] = *(const short8*)&vb[kt * 2048 + (jd * 16 + lm) * 32 + quad * 8];
      float2 bb[2][4];
#pragma unroll
      for (int g = 0; g < 2; ++g)
#pragma unroll
        for (int r = 0; r < 4; ++r) {
          int i = t * 32 + g * 16 + quad * 4 + r;
          bb[g][r] = *(const float2*)&rb[((size_t)kt * NS + i) * 32 + 2 * lm];
        }

      floatx4 sA[2], sB[2];
      __builtin_amdgcn_s_setprio(1);
#pragma unroll
      for (int g = 0; g < 2; ++g) {
        floatx4 s = zero4;
        s = __builtin_amdgcn_mfma_f32_16x16x32_bf16(aq[g][0], bkA0, s, 0, 0, 0);
        s = __builtin_amdgcn_mfma_f32_16x16x32_bf16(aq[g][1], bkA1, s, 0, 0, 0);
        sA[g] = s;
        s = zero4;
        s = __builtin_amdgcn_mfma_f32_16x16x32_bf16(aq[g][0], bkB0, s, 0, 0, 0);
        s = __builtin_amdgcn_mfma_f32_16x16x32_bf16(aq[g][1], bkB1, s, 0, 0, 0);
        sB[g] = s;
      }
      __builtin_amdgcn_s_setprio(0);

      const bool diag = (kt == t);  // wave-uniform
#pragma unroll
      for (int g = 0; g < 2; ++g) {
        unsigned pw[4];
#pragma unroll
        for (int r = 0; r < 4; ++r) {
          float p0 = __builtin_amdgcn_exp2f(fmaf(sA[g][r], SCL, bb[g][r].x));
          float p1 = __builtin_amdgcn_exp2f(fmaf(sB[g][r], SCL, bb[g][r].y));
          if (diag) {
            int i = t * 32 + g * 16 + quad * 4 + r;
            if (kvA > i) p0 = 0.f;
            if (kvB > i) p1 = 0.f;
          }
          lsum[g][r] += p0 + p1;
          unsigned pk;
          asm("v_cvt_pk_bf16_f32 %0, %1, %2" : "=v"(pk) : "v"(p0), "v"(p1));
          sP[wid][(g * 16 + quad * 4 + r) * PSTR + lm] = (ushort_t)(pk & 0xffffu);
          sP[wid][(g * 16 + quad * 4 + r) * PSTR + 16 + lm] = (ushort_t)(pk >> 16);
          half2v hp = __builtin_amdgcn_cvt_pkrtz(p0, p1);
          pw[r] = *(unsigned*)&hp;
        }
        uint4 pq = {pw[0], pw[1], pw[2], pw[3]};
        pp[(size_t)kt * 128 + g * 64] = pq;  // fire-and-forget, 1KB/instr
      }

      __builtin_amdgcn_s_setprio(1);
#pragma unroll
      for (int g = 0; g < 2; ++g) {
        short8 ap = *(const short8*)&sP[wid][(g * 16 + lm) * PSTR + quad * 8];
#pragma unroll
        for (int jd = 0; jd < 4; ++jd)
          O[g][jd] = __builtin_amdgcn_mfma_f32_16x16x32_bf16(ap, bv2[jd], O[g][jd], 0, 0, 0);
      }
      __builtin_amdgcn_s_setprio(0);
    }

#pragma unroll
    for (int off = 1; off < 16; off <<= 1)
#pragma unroll
      for (int g = 0; g < 2; ++g)
#pragma unroll
        for (int r = 0; r < 4; ++r) lsum[g][r] += __shfl_xor(lsum[g][r], off, 64);

#pragma unroll
    for (int g = 0; g < 2; ++g) {
      float rinv[4];
#pragma unroll
      for (int r = 0; r < 4; ++r) rinv[r] = 1.f / lsum[g][r];
#pragma unroll
      for (int jd = 0; jd < 4; ++jd)
#pragma unroll
        for (int r = 0; r < 4; ++r) {
          int i = t * 32 + g * 16 + quad * 4 + r;
          ctxb[((size_t)b * NS + i) * ND + h * NDK + jd * 16 + lm] =
              f2bf(O[g][jd][r] * rinv[r]);
        }
      if (lm == 0) {
#pragma unroll
        for (int r = 0; r < 4; ++r) {
          int i = t * 32 + g * 16 + quad * 4 + r;
          cst[(size_t)bh * NS + i] = rinv[r];
        }
      }
    }
  }
}

// ---------------------------------------------------------------- attn_mean_p
// Streaming mean over heads from the P scratch written by flash_attn.
// grid (32 b, 15 t, 15 kt), 1 wave/block. kt>t tiles: zero-fill.
__global__ __launch_bounds__(64)
void attn_mean_p(const uint4* __restrict__ pscr, const float* __restrict__ cst,
                 float* __restrict__ am) {
  const int b = blockIdx.x, t = blockIdx.y, kt = blockIdx.z;
  const int lane = threadIdx.x;
  const int lm = lane & 15, quad = lane >> 4;
  float* outp = am + ((size_t)b * NS + t * 32) * NS + (size_t)kt * 32;
  if (kt > t) {
#pragma unroll
    for (int g = 0; g < 2; ++g)
#pragma unroll
      for (int r = 0; r < 4; ++r) {
        int row = g * 16 + quad * 4 + r;
        outp[(size_t)row * NS + lm] = 0.f;
        outp[(size_t)row * NS + 16 + lm] = 0.f;
      }
    return;
  }
  const int m = (t * (t + 1)) / 2 + kt;
  float a0[2][4], a1[2][4];
#pragma unroll
  for (int g = 0; g < 2; ++g)
#pragma unroll
    for (int r = 0; r < 4; ++r) { a0[g][r] = 0.f; a1[g][r] = 0.f; }

#pragma unroll
  for (int h = 0; h < NH; ++h) {
    const uint4* pp = pscr + ((size_t)(b * NH + h) * 120 + m) * 128 + lane;
    uint4 q0 = pp[0];        // g=0: rows quad*4..+3 of 0..15, cols lm/16+lm
    uint4 q1 = pp[64];       // g=1
    unsigned pu[8] = {q0.x, q0.y, q0.z, q0.w, q1.x, q1.y, q1.z, q1.w};
    const float* cp = cst + (size_t)(b * NH + h) * NS + t * 32 + quad * 4;
    float4 rv0 = *(const float4*)cp;
    float4 rv1 = *(const float4*)(cp + 16);
    float rv[8] = {rv0.x, rv0.y, rv0.z, rv0.w, rv1.x, rv1.y, rv1.z, rv1.w};
#pragma unroll
    for (int g = 0; g < 2; ++g)
#pragma unroll
      for (int r = 0; r < 4; ++r) {
        half2v hp = *(half2v*)&pu[g * 4 + r];
        a0[g][r] = fmaf((float)hp.x, rv[g * 4 + r], a0[g][r]);
        a1[g][r] = fmaf((float)hp.y, rv[g * 4 + r], a1[g][r]);
      }
  }

#pragma unroll
  for (int g = 0; g < 2; ++g)
#pragma unroll
    for (int r = 0; r < 4; ++r) {
      int row = g * 16 + quad * 4 + r;
      outp[(size_t)row * NS + lm] = a0[g][r] * 0.125f;
      outp[(size_t)row * NS + 16 + lm] = a1[g][r] * 0.125f;
    }
}

// ---------------------------------------------------------------- out_gemm
__global__ __launch_bounds__(256)
void out_gemm(const ushort_t* __restrict__ ctxb, const ushort_t* __restrict__ woT,
              const float* __restrict__ bo, float* __restrict__ out) {
  __shared__ __align__(16) ushort_t sA[128 * 64];
  __shared__ __align__(16) ushort_t sB[128 * 64];
  const int tid = threadIdx.x;
  const int wid = tid >> 6, lane = tid & 63;
  const int lm = lane & 15, quad = lane >> 4;
  const int wr = wid >> 1, wc = wid & 1;
  const int row0 = blockIdx.x * 128;
  const int col0 = blockIdx.y * 128;

  floatx4 zero4 = {0.f, 0.f, 0.f, 0.f};
  floatx4 acc[4][4];
#pragma unroll
  for (int i = 0; i < 4; ++i)
#pragma unroll
    for (int j = 0; j < 4; ++j) acc[i][j] = zero4;

  for (int k0 = 0; k0 < ND; k0 += 64) {
#pragma unroll
    for (int c = 0; c < 4; ++c) {
      int li = c * 256 + tid;
      int row = li >> 3, kc = li & 7;
      int kcs = kc ^ (row & 7);
      GLOAD_LDS16(ctxb + (row0 + row) * ND + k0 + kcs * 8, sA + (c * 256 + wid * 64) * 8);
      GLOAD_LDS16(woT + (col0 + row) * ND + k0 + kcs * 8, sB + (c * 256 + wid * 64) * 8);
    }
    __syncthreads();
#pragma unroll
    for (int h2 = 0; h2 < 2; ++h2) {
      short8 a[4], b[4];
#pragma unroll
      for (int i = 0; i < 4; ++i) {
        int row = wr * 64 + i * 16 + lm;
        a[i] = *(const short8*)&sA[row * 64 + (((h2 << 2) | quad) ^ (lm & 7)) * 8];
      }
#pragma unroll
      for (int j = 0; j < 4; ++j) {
        int row = wc * 64 + j * 16 + lm;
        b[j] = *(const short8*)&sB[row * 64 + (((h2 << 2) | quad) ^ (lm & 7)) * 8];
      }
#pragma unroll
      for (int i = 0; i < 4; ++i)
#pragma unroll
        for (int j = 0; j < 4; ++j)
          acc[i][j] = __builtin_amdgcn_mfma_f32_16x16x32_bf16(a[i], b[j], acc[i][j], 0, 0, 0);
    }
    __syncthreads();
  }

  float bsv[4];
#pragma unroll
  for (int j = 0; j < 4; ++j) bsv[j] = bo[col0 + wc * 64 + j * 16 + lm];

#pragma unroll
  for (int i = 0; i < 4; ++i)
#pragma unroll
    for (int j = 0; j < 4; ++j)
#pragma unroll
      for (int r = 0; r < 4; ++r) {
        int m = row0 + wr * 64 + i * 16 + quad * 4 + r;
        int n = col0 + wc * 64 + j * 16 + lm;
        out[m * ND + n] = acc[i][j][r] + bsv[j];
      }
}

// ---------------------------------------------------------------- launch
extern "C" void kernel_launch(void* const* d_in, const int* in_sizes, int n_in,
                              void* d_out, int out_size, void* d_ws, size_t ws_size,
                              hipStream_t stream) {
  const float* x  = (const float*)d_in[0];
  const float* wq = (const float*)d_in[1];
  const float* bq = (const float*)d_in[2];
  const float* wk = (const float*)d_in[3];
  const float* bk = (const float*)d_in[4];
  const float* wv = (const float*)d_in[5];
  const float* bv = (const float*)d_in[6];
  const float* wo = (const float*)d_in[7];
  const float* bo = (const float*)d_in[8];
  const float* rel_bias = (const float*)d_in[9];

  char* w = (char*)d_ws;
  ushort_t* xb  = (ushort_t*)w;                       // 15,728,640 B
  ushort_t* wqT = (ushort_t*)(w + 15728640);          // 4 x 524,288 B
  ushort_t* wkT = wqT + 262144;
  ushort_t* wvT = wkT + 262144;
  ushort_t* woT = wvT + 262144;
  ushort_t* qb  = (ushort_t*)(w + 15728640 + 4 * 524288);
  ushort_t* kb  = qb + 7864320;
  ushort_t* vtil = kb + 7864320;                      // tiled V
  ushort_t* ctxb = vtil + 7864320;
  float* cstat = (float*)(w + 80740352);              // rinv [bh][i], 491,520 B
  uint4* pscr = (uint4*)(w + 81264640);               // P scratch, 62,914,560 B
  // rbt (14,745,600 B) aliases xb — xb is dead after qkv_gemm
  float* rbt = (float*)w;

  float* out0 = (float*)d_out;        // [32,480,512]
  float* attn_mean = out0 + 7864320;  // [32,480,480]

  cvt_xw<<<dim3(8704), dim3(256), 0, stream>>>(x, wq, wk, wv, wo, xb, wqT, wkT, wvT, woT);
  qkv_gemm<<<dim3(128, 4, 3), dim3(256), 0, stream>>>(xb, wqT, wkT, wvT, bq, bk, bv,
                                                      qb, kb, vtil);
  cvt_rbt<<<dim3(15, 30, 8), dim3(256), 0, stream>>>(rel_bias, rbt);
  flash_attn<<<dim3(256, 2), dim3(256), 0, stream>>>(qb, kb, vtil, rbt, ctxb, cstat, pscr);
  attn_mean_p<<<dim3(32, 15, 15), dim3(64), 0, stream>>>(pscr, cstat, attn_mean);
  out_gemm<<<dim3(120, 4), dim3(256), 0, stream>>>(ctxb, woT, bo, out0);
}

// Round 10
// 220.853 us; speedup vs baseline: 1.5397x; 1.0252x over previous
//
#include <hip/hip_runtime.h>
#include <hip/hip_bf16.h>

// B=32, S=480, D=512, H=8, dk=64. Outputs: out[32,480,512] fp32,
// attn_mean[32,480,480] fp32, concatenated in d_out.
//
// Pipeline (bf16 MFMA 16x16x32), 6 launches:
//  1. cvt_xw     : x fp32->bf16 (blocks <7680) + w* transpose (blocks >=7680)
//  2. qkv_gemm   : z<2 -> q/k gemm, z==2 -> V tiled gemm. 2-PHASE DOUBLE-
//                  BUFFERED LDS: stage tile t+1 BEFORE computing tile t, one
//                  barrier/iter -> global_load_lds latency hides under MFMAs
//                  (was: stage; sync(vmcnt0 drain, ~75% of iter); mfma; sync).
//  3. cvt_rbt    : rel_bias*log2e -> paired rbt (MUST follow qkv: aliases xb)
//  4. flash_attn : balanced pairing slot s<7 -> {s,13-s}, s==7 -> {14};
//                  straight loop, exp2, diag-only mask, cvt_pk, setprio.
//                  P tiles fp16 -> pscr coalesced; cst = 1/lsum [bh][i].
//  5. attn_mean_p: streaming mean: read pscr (8 heads) * rinv -> fp32.
//  6. out_gemm   : ctx @ woT + bo -> fp32, same 2-phase dbuf.

typedef unsigned short ushort_t;
typedef __attribute__((ext_vector_type(8))) short short8;
typedef __attribute__((ext_vector_type(4))) float floatx4;
typedef __attribute__((ext_vector_type(2))) __fp16 half2v;

#define NB 32
#define NS 480
#define ND 512
#define NH 8
#define NDK 64
#define MAXLEN 500
#define PSTR 36   // sP row stride (ushorts): b128 frag reads <=2-way bank alias
#define SCL 0.18033688f  // 0.125 * log2(e)

__device__ __forceinline__ ushort_t f2bf(float f) {
  union { float f; unsigned u; } v; v.f = f;
  unsigned r = v.u + 0x7FFFu + ((v.u >> 16) & 1u);
  return (ushort_t)(r >> 16);
}

#define GLOAD_LDS16(g, l)                                                      \
  __builtin_amdgcn_global_load_lds(                                            \
      (const __attribute__((address_space(1))) void*)(g),                      \
      (__attribute__((address_space(3))) void*)(l), 16, 0, 0)

// ---------------------------------------------------------------- cvt_xw
// blocks [0,7680): x fp32->bf16 vectorized. blocks [7680,8704): w transpose.
__global__ __launch_bounds__(256)
void cvt_xw(const float* __restrict__ x, const float* __restrict__ wq,
            const float* __restrict__ wk, const float* __restrict__ wv,
            const float* __restrict__ wo, ushort_t* __restrict__ xb,
            ushort_t* __restrict__ wqT, ushort_t* __restrict__ wkT,
            ushort_t* __restrict__ wvT, ushort_t* __restrict__ woT) {
  __shared__ float t[32][33];
  const int bid = blockIdx.x;
  if (bid < 7680) {
    int idx = bid * 256 + threadIdx.x;
    float4 v = ((const float4*)x)[idx];
    ushort4 o;
    o.x = f2bf(v.x); o.y = f2bf(v.y); o.z = f2bf(v.z); o.w = f2bf(v.w);
    ((ushort4*)xb)[idx] = o;
    return;
  }
  const int q = bid - 7680;
  const int z = q >> 8;
  const float* w = (z == 0) ? wq : (z == 1) ? wk : (z == 2) ? wv : wo;
  ushort_t* wT = (z == 0) ? wqT : (z == 1) ? wkT : (z == 2) ? wvT : woT;
  int k0 = (q & 15) * 32, n0 = ((q >> 4) & 15) * 32;
  int tx = threadIdx.x & 31, ty = threadIdx.x >> 5;
#pragma unroll
  for (int yy = 0; yy < 4; ++yy)
    t[ty + yy * 8][tx] = w[(k0 + ty + yy * 8) * ND + n0 + tx];
  __syncthreads();
#pragma unroll
  for (int yy = 0; yy < 4; ++yy)
    wT[(n0 + ty + yy * 8) * ND + k0 + tx] = f2bf(t[tx][ty + yy * 8]);
}

// ---------------------------------------------------------------- cvt_rbt
__global__ void cvt_rbt(const float* __restrict__ rel_bias, float* __restrict__ rbt) {
  int kt = blockIdx.x, ib = blockIdx.y, h = blockIdx.z;
  int lm = threadIdx.x & 15, ii = threadIdx.x >> 4;
  int i = ib * 16 + ii;
  float f0 = rel_bias[((size_t)h * MAXLEN + i) * MAXLEN + kt * 32 + lm] * 1.44269504f;
  float f1 = rel_bias[((size_t)h * MAXLEN + i) * MAXLEN + kt * 32 + 16 + lm] * 1.44269504f;
  float2 o = {f0, f1};
  *(float2*)&rbt[(((size_t)h * 15 + kt) * NS + i) * 32 + 2 * lm] = o;
}

// ---------------------------------------------------------------- qkv_gemm
// z in {0,1}: q/k gemm (blocks x<120). z==2: V tiled gemm, b=x>>2.
// 2-phase double-buffered LDS staging.
__global__ __launch_bounds__(256)
void qkv_gemm(const ushort_t* __restrict__ xb,
              const ushort_t* __restrict__ wqT, const ushort_t* __restrict__ wkT,
              const ushort_t* __restrict__ wvT,
              const float* __restrict__ bq, const float* __restrict__ bk,
              const float* __restrict__ bv,
              ushort_t* __restrict__ qb, ushort_t* __restrict__ kb,
              ushort_t* __restrict__ vtil) {
  __shared__ __align__(16) ushort_t sA[2][128 * 64];
  __shared__ __align__(16) ushort_t sB[2][128 * 64];
  const int tid = threadIdx.x;
  const int wid = tid >> 6, lane = tid & 63;
  const int lm = lane & 15, quad = lane >> 4;
  const int wr = wid >> 1, wc = wid & 1;
  const int z = blockIdx.z;

  floatx4 zero4 = {0.f, 0.f, 0.f, 0.f};
  floatx4 acc[4][4];
#pragma unroll
  for (int i = 0; i < 4; ++i)
#pragma unroll
    for (int j = 0; j < 4; ++j) acc[i][j] = zero4;

  // staging geometry (shared by both paths)
  const int srow_ = tid >> 3, skc = tid & 7;
  const int skcs = skc ^ (srow_ & 7);

  if (z < 2) {
    if (blockIdx.x >= 120) return;
    const int row0 = blockIdx.x * 128;
    const int col0 = blockIdx.y * 128;
    const ushort_t* Bt = (z == 0) ? wqT : wkT;
    const float* bias = (z == 0) ? bq : bk;

    // prologue: stage k0=0 into buf 0
#pragma unroll
    for (int c = 0; c < 4; ++c) {
      int row = c * 32 + srow_;
      GLOAD_LDS16(xb + (row0 + row) * ND + skcs * 8, &sA[0][(c * 256 + wid * 64) * 8]);
      GLOAD_LDS16(Bt + (col0 + row) * ND + skcs * 8, &sB[0][(c * 256 + wid * 64) * 8]);
    }
    __syncthreads();

    int buf = 0;
    for (int t = 0; t < 8; ++t) {
      if (t < 7) {
        int k0n = (t + 1) * 64;
#pragma unroll
        for (int c = 0; c < 4; ++c) {
          int row = c * 32 + srow_;
          GLOAD_LDS16(xb + (row0 + row) * ND + k0n + skcs * 8,
                      &sA[buf ^ 1][(c * 256 + wid * 64) * 8]);
          GLOAD_LDS16(Bt + (col0 + row) * ND + k0n + skcs * 8,
                      &sB[buf ^ 1][(c * 256 + wid * 64) * 8]);
        }
      }
#pragma unroll
      for (int h2 = 0; h2 < 2; ++h2) {
        short8 a[4], b[4];
#pragma unroll
        for (int i = 0; i < 4; ++i) {
          int row = wr * 64 + i * 16 + lm;
          a[i] = *(const short8*)&sA[buf][row * 64 + (((h2 << 2) | quad) ^ (lm & 7)) * 8];
        }
#pragma unroll
        for (int j = 0; j < 4; ++j) {
          int row = wc * 64 + j * 16 + lm;
          b[j] = *(const short8*)&sB[buf][row * 64 + (((h2 << 2) | quad) ^ (lm & 7)) * 8];
        }
#pragma unroll
        for (int i = 0; i < 4; ++i)
#pragma unroll
          for (int j = 0; j < 4; ++j)
            acc[i][j] = __builtin_amdgcn_mfma_f32_16x16x32_bf16(a[i], b[j], acc[i][j], 0, 0, 0);
      }
      __syncthreads();
      buf ^= 1;
    }

    float bsv[4];
#pragma unroll
    for (int j = 0; j < 4; ++j) bsv[j] = bias[col0 + wc * 64 + j * 16 + lm];

#pragma unroll
    for (int i = 0; i < 4; ++i)
#pragma unroll
      for (int j = 0; j < 4; ++j)
#pragma unroll
        for (int r = 0; r < 4; ++r) {
          int m = row0 + wr * 64 + i * 16 + quad * 4 + r;
          int n = col0 + wc * 64 + j * 16 + lm;
          float val = acc[i][j][r] + bsv[j];
          int bb = m / NS, s = m - bb * NS;
          int h = n >> 6, d = n & 63;
          ushort_t o = f2bf(val);
          if (z == 0) qb[((bb * NH + h) * NS + s) * NDK + d] = o;
          else        kb[((bb * NH + h) * NS + s) * NDK + d] = o;
        }
  } else {
    const int b = blockIdx.x >> 2;
    const int row0 = (blockIdx.x & 3) * 128;  // dd
    const int col0 = blockIdx.y * 128;        // s
    const ushort_t* xbb = xb + (size_t)b * NS * ND;

#pragma unroll
    for (int c = 0; c < 4; ++c) {
      int row = c * 32 + srow_;
      GLOAD_LDS16(wvT + (row0 + row) * ND + skcs * 8, &sA[0][(c * 256 + wid * 64) * 8]);
      int sr = min(col0 + row, NS - 1);
      GLOAD_LDS16(xbb + sr * ND + skcs * 8, &sB[0][(c * 256 + wid * 64) * 8]);
    }
    __syncthreads();

    int buf = 0;
    for (int t = 0; t < 8; ++t) {
      if (t < 7) {
        int k0n = (t + 1) * 64;
#pragma unroll
        for (int c = 0; c < 4; ++c) {
          int row = c * 32 + srow_;
          GLOAD_LDS16(wvT + (row0 + row) * ND + k0n + skcs * 8,
                      &sA[buf ^ 1][(c * 256 + wid * 64) * 8]);
          int sr = min(col0 + row, NS - 1);
          GLOAD_LDS16(xbb + sr * ND + k0n + skcs * 8,
                      &sB[buf ^ 1][(c * 256 + wid * 64) * 8]);
        }
      }
#pragma unroll
      for (int h2 = 0; h2 < 2; ++h2) {
        short8 a[4], b2[4];
#pragma unroll
        for (int i = 0; i < 4; ++i) {
          int row = wr * 64 + i * 16 + lm;
          a[i] = *(const short8*)&sA[buf][row * 64 + (((h2 << 2) | quad) ^ (lm & 7)) * 8];
        }
#pragma unroll
        for (int j = 0; j < 4; ++j) {
          int row = wc * 64 + j * 16 + lm;
          b2[j] = *(const short8*)&sB[buf][row * 64 + (((h2 << 2) | quad) ^ (lm & 7)) * 8];
        }
#pragma unroll
        for (int i = 0; i < 4; ++i)
#pragma unroll
          for (int j = 0; j < 4; ++j)
            acc[i][j] = __builtin_amdgcn_mfma_f32_16x16x32_bf16(a[i], b2[j], acc[i][j], 0, 0, 0);
      }
      __syncthreads();
      buf ^= 1;
    }

#pragma unroll
    for (int i = 0; i < 4; ++i)
#pragma unroll
      for (int r = 0; r < 4; ++r) {
        int m = row0 + wr * 64 + i * 16 + quad * 4 + r;  // dd = h*64 + d
        float bias = bv[m];
#pragma unroll
        for (int j = 0; j < 4; ++j) {
          int n = col0 + wc * 64 + j * 16 + lm;  // s
          if (n < NS) {
            size_t idx = (((size_t)b * NH + (m >> 6)) * 15 + (n >> 5)) * 2048 +
                         (m & 63) * 32 + (n & 31);
            vtil[idx] = f2bf(acc[i][j][r] + bias);
          }
        }
      }
  }
}

// ---------------------------------------------------------------- flash_attn
// grid (256 bh, 2). slot = y*4+wid in 0..7; slot<7 -> tiles {slot, 13-slot},
// slot==7 -> {14}: every wave runs exactly 15 kt-iterations (load-balanced).
__global__ __launch_bounds__(256)
void flash_attn(const ushort_t* __restrict__ qb, const ushort_t* __restrict__ kb,
                const ushort_t* __restrict__ vtil, const float* __restrict__ rbt,
                ushort_t* __restrict__ ctxb, float* __restrict__ cst,
                uint4* __restrict__ pscr) {
  const int bh = blockIdx.x;
  const int b = bh >> 3, h = bh & 7;
  const int tid = threadIdx.x;
  const int wid = tid >> 6, lane = tid & 63;
  const int lm = lane & 15, quad = lane >> 4;

  __shared__ __align__(16) ushort_t sP[4][32 * PSTR];

  const int slot = blockIdx.y * 4 + wid;  // 0..7
  const int tA = (slot == 7) ? 14 : slot;
  const int tB = (slot == 7) ? -1 : 13 - slot;

  const ushort_t* qh = qb + (size_t)bh * NS * NDK;
  const ushort_t* kh = kb + (size_t)bh * NS * NDK;
  const ushort_t* vb = vtil + (size_t)bh * 15 * 2048;
  const float* rb = rbt + (size_t)h * 15 * NS * 32;

#pragma unroll 1
  for (int ti = 0; ti < 2; ++ti) {
    const int t = (ti == 0) ? tA : tB;
    if (t < 0) break;
    const int nkt = t + 1;
    uint4* pp = pscr + ((size_t)(bh * 120 + (t * (t + 1)) / 2)) * 128 + lane;

    short8 aq[2][2];
#pragma unroll
    for (int g = 0; g < 2; ++g) {
      aq[g][0] = *(const short8*)&qh[(t * 32 + g * 16 + lm) * NDK + quad * 8];
      aq[g][1] = *(const short8*)&qh[(t * 32 + g * 16 + lm) * NDK + 32 + quad * 8];
    }

    float lsum[2][4];
    floatx4 O[2][4];
    floatx4 zero4 = {0.f, 0.f, 0.f, 0.f};
#pragma unroll
    for (int g = 0; g < 2; ++g) {
#pragma unroll
      for (int r = 0; r < 4; ++r) lsum[g][r] = 0.f;
#pragma unroll
      for (int jd = 0; jd < 4; ++jd) O[g][jd] = zero4;
    }

    for (int kt = 0; kt < nkt; ++kt) {
      const int kvA = kt * 32 + lm;
      const int kvB = kvA + 16;
      short8 bkA0 = *(const short8*)&kh[kvA * NDK + quad * 8];
      short8 bkA1 = *(const short8*)&kh[kvA * NDK + 32 + quad * 8];
      short8 bkB0 = *(const short8*)&kh[kvB * NDK + quad * 8];
      short8 bkB1 = *(const short8*)&kh[kvB * NDK + 32 + quad * 8];
      short8 bv2[4];
#pragma unroll
      for (int jd = 0; jd < 4; ++jd)
        bv2[jd] = *(const short8*)&vb[kt * 2048 + (jd * 16 + lm) * 32 + quad * 8];
      float2 bb[2][4];
#pragma unroll
      for (int g = 0; g < 2; ++g)
#pragma unroll
        for (int r = 0; r < 4; ++r) {
          int i = t * 32 + g * 16 + quad * 4 + r;
          bb[g][r] = *(const float2*)&rb[((size_t)kt * NS + i) * 32 + 2 * lm];
        }

      floatx4 sA[2], sB[2];
      __builtin_amdgcn_s_setprio(1);
#pragma unroll
      for (int g = 0; g < 2; ++g) {
        floatx4 s = zero4;
        s = __builtin_amdgcn_mfma_f32_16x16x32_bf16(aq[g][0], bkA0, s, 0, 0, 0);
        s = __builtin_amdgcn_mfma_f32_16x16x32_bf16(aq[g][1], bkA1, s, 0, 0, 0);
        sA[g] = s;
        s = zero4;
        s = __builtin_amdgcn_mfma_f32_16x16x32_bf16(aq[g][0], bkB0, s, 0, 0, 0);
        s = __builtin_amdgcn_mfma_f32_16x16x32_bf16(aq[g][1], bkB1, s, 0, 0, 0);
        sB[g] = s;
      }
      __builtin_amdgcn_s_setprio(0);

      const bool diag = (kt == t);  // wave-uniform
#pragma unroll
      for (int g = 0; g < 2; ++g) {
        unsigned pw[4];
#pragma unroll
        for (int r = 0; r < 4; ++r) {
          float p0 = __builtin_amdgcn_exp2f(fmaf(sA[g][r], SCL, bb[g][r].x));
          float p1 = __builtin_amdgcn_exp2f(fmaf(sB[g][r], SCL, bb[g][r].y));
          if (diag) {
            int i = t * 32 + g * 16 + quad * 4 + r;
            if (kvA > i) p0 = 0.f;
            if (kvB > i) p1 = 0.f;
          }
          lsum[g][r] += p0 + p1;
          unsigned pk;
          asm("v_cvt_pk_bf16_f32 %0, %1, %2" : "=v"(pk) : "v"(p0), "v"(p1));
          sP[wid][(g * 16 + quad * 4 + r) * PSTR + lm] = (ushort_t)(pk & 0xffffu);
          sP[wid][(g * 16 + quad * 4 + r) * PSTR + 16 + lm] = (ushort_t)(pk >> 16);
          half2v hp = __builtin_amdgcn_cvt_pkrtz(p0, p1);
          pw[r] = *(unsigned*)&hp;
        }
        uint4 pq = {pw[0], pw[1], pw[2], pw[3]};
        pp[(size_t)kt * 128 + g * 64] = pq;  // fire-and-forget, 1KB/instr
      }

      __builtin_amdgcn_s_setprio(1);
#pragma unroll
      for (int g = 0; g < 2; ++g) {
        short8 ap = *(const short8*)&sP[wid][(g * 16 + lm) * PSTR + quad * 8];
#pragma unroll
        for (int jd = 0; jd < 4; ++jd)
          O[g][jd] = __builtin_amdgcn_mfma_f32_16x16x32_bf16(ap, bv2[jd], O[g][jd], 0, 0, 0);
      }
      __builtin_amdgcn_s_setprio(0);
    }

#pragma unroll
    for (int off = 1; off < 16; off <<= 1)
#pragma unroll
      for (int g = 0; g < 2; ++g)
#pragma unroll
        for (int r = 0; r < 4; ++r) lsum[g][r] += __shfl_xor(lsum[g][r], off, 64);

#pragma unroll
    for (int g = 0; g < 2; ++g) {
      float rinv[4];
#pragma unroll
      for (int r = 0; r < 4; ++r) rinv[r] = 1.f / lsum[g][r];
#pragma unroll
      for (int jd = 0; jd < 4; ++jd)
#pragma unroll
        for (int r = 0; r < 4; ++r) {
          int i = t * 32 + g * 16 + quad * 4 + r;
          ctxb[((size_t)b * NS + i) * ND + h * NDK + jd * 16 + lm] =
              f2bf(O[g][jd][r] * rinv[r]);
        }
      if (lm == 0) {
#pragma unroll
        for (int r = 0; r < 4; ++r) {
          int i = t * 32 + g * 16 + quad * 4 + r;
          cst[(size_t)bh * NS + i] = rinv[r];
        }
      }
    }
  }
}

// ---------------------------------------------------------------- attn_mean_p
__global__ __launch_bounds__(64)
void attn_mean_p(const uint4* __restrict__ pscr, const float* __restrict__ cst,
                 float* __restrict__ am) {
  const int b = blockIdx.x, t = blockIdx.y, kt = blockIdx.z;
  const int lane = threadIdx.x;
  const int lm = lane & 15, quad = lane >> 4;
  float* outp = am + ((size_t)b * NS + t * 32) * NS + (size_t)kt * 32;
  if (kt > t) {
#pragma unroll
    for (int g = 0; g < 2; ++g)
#pragma unroll
      for (int r = 0; r < 4; ++r) {
        int row = g * 16 + quad * 4 + r;
        outp[(size_t)row * NS + lm] = 0.f;
        outp[(size_t)row * NS + 16 + lm] = 0.f;
      }
    return;
  }
  const int m = (t * (t + 1)) / 2 + kt;
  float a0[2][4], a1[2][4];
#pragma unroll
  for (int g = 0; g < 2; ++g)
#pragma unroll
    for (int r = 0; r < 4; ++r) { a0[g][r] = 0.f; a1[g][r] = 0.f; }

#pragma unroll
  for (int h = 0; h < NH; ++h) {
    const uint4* pp = pscr + ((size_t)(b * NH + h) * 120 + m) * 128 + lane;
    uint4 q0 = pp[0];        // g=0: rows quad*4..+3 of 0..15, cols lm/16+lm
    uint4 q1 = pp[64];       // g=1
    unsigned pu[8] = {q0.x, q0.y, q0.z, q0.w, q1.x, q1.y, q1.z, q1.w};
    const float* cp = cst + (size_t)(b * NH + h) * NS + t * 32 + quad * 4;
    float4 rv0 = *(const float4*)cp;
    float4 rv1 = *(const float4*)(cp + 16);
    float rv[8] = {rv0.x, rv0.y, rv0.z, rv0.w, rv1.x, rv1.y, rv1.z, rv1.w};
#pragma unroll
    for (int g = 0; g < 2; ++g)
#pragma unroll
      for (int r = 0; r < 4; ++r) {
        half2v hp = *(half2v*)&pu[g * 4 + r];
        a0[g][r] = fmaf((float)hp.x, rv[g * 4 + r], a0[g][r]);
        a1[g][r] = fmaf((float)hp.y, rv[g * 4 + r], a1[g][r]);
      }
  }

#pragma unroll
  for (int g = 0; g < 2; ++g)
#pragma unroll
    for (int r = 0; r < 4; ++r) {
      int row = g * 16 + quad * 4 + r;
      outp[(size_t)row * NS + lm] = a0[g][r] * 0.125f;
      outp[(size_t)row * NS + 16 + lm] = a1[g][r] * 0.125f;
    }
}

// ---------------------------------------------------------------- out_gemm
// ctx @ woT + bo, 2-phase double-buffered LDS staging.
__global__ __launch_bounds__(256)
void out_gemm(const ushort_t* __restrict__ ctxb, const ushort_t* __restrict__ woT,
              const float* __restrict__ bo, float* __restrict__ out) {
  __shared__ __align__(16) ushort_t sA[2][128 * 64];
  __shared__ __align__(16) ushort_t sB[2][128 * 64];
  const int tid = threadIdx.x;
  const int wid = tid >> 6, lane = tid & 63;
  const int lm = lane & 15, quad = lane >> 4;
  const int wr = wid >> 1, wc = wid & 1;
  const int row0 = blockIdx.x * 128;
  const int col0 = blockIdx.y * 128;
  const int srow_ = tid >> 3, skc = tid & 7;
  const int skcs = skc ^ (srow_ & 7);

  floatx4 zero4 = {0.f, 0.f, 0.f, 0.f};
  floatx4 acc[4][4];
#pragma unroll
  for (int i = 0; i < 4; ++i)
#pragma unroll
    for (int j = 0; j < 4; ++j) acc[i][j] = zero4;

#pragma unroll
  for (int c = 0; c < 4; ++c) {
    int row = c * 32 + srow_;
    GLOAD_LDS16(ctxb + (row0 + row) * ND + skcs * 8, &sA[0][(c * 256 + wid * 64) * 8]);
    GLOAD_LDS16(woT + (col0 + row) * ND + skcs * 8, &sB[0][(c * 256 + wid * 64) * 8]);
  }
  __syncthreads();

  int buf = 0;
  for (int t = 0; t < 8; ++t) {
    if (t < 7) {
      int k0n = (t + 1) * 64;
#pragma unroll
      for (int c = 0; c < 4; ++c) {
        int row = c * 32 + srow_;
        GLOAD_LDS16(ctxb + (row0 + row) * ND + k0n + skcs * 8,
                    &sA[buf ^ 1][(c * 256 + wid * 64) * 8]);
        GLOAD_LDS16(woT + (col0 + row) * ND + k0n + skcs * 8,
                    &sB[buf ^ 1][(c * 256 + wid * 64) * 8]);
      }
    }
#pragma unroll
    for (int h2 = 0; h2 < 2; ++h2) {
      short8 a[4], b[4];
#pragma unroll
      for (int i = 0; i < 4; ++i) {
        int row = wr * 64 + i * 16 + lm;
        a[i] = *(const short8*)&sA[buf][row * 64 + (((h2 << 2) | quad) ^ (lm & 7)) * 8];
      }
#pragma unroll
      for (int j = 0; j < 4; ++j) {
        int row = wc * 64 + j * 16 + lm;
        b[j] = *(const short8*)&sB[buf][row * 64 + (((h2 << 2) | quad) ^ (lm & 7)) * 8];
      }
#pragma unroll
      for (int i = 0; i < 4; ++i)
#pragma unroll
        for (int j = 0; j < 4; ++j)
          acc[i][j] = __builtin_amdgcn_mfma_f32_16x16x32_bf16(a[i], b[j], acc[i][j], 0, 0, 0);
    }
    __syncthreads();
    buf ^= 1;
  }

  float bsv[4];
#pragma unroll
  for (int j = 0; j < 4; ++j) bsv[j] = bo[col0 + wc * 64 + j * 16 + lm];

#pragma unroll
  for (int i = 0; i < 4; ++i)
#pragma unroll
    for (int j = 0; j < 4; ++j)
#pragma unroll
      for (int r = 0; r < 4; ++r) {
        int m = row0 + wr * 64 + i * 16 + quad * 4 + r;
        int n = col0 + wc * 64 + j * 16 + lm;
        out[m * ND + n] = acc[i][j][r] + bsv[j];
      }
}

// ---------------------------------------------------------------- launch
extern "C" void kernel_launch(void* const* d_in, const int* in_sizes, int n_in,
                              void* d_out, int out_size, void* d_ws, size_t ws_size,
                              hipStream_t stream) {
  const float* x  = (const float*)d_in[0];
  const float* wq = (const float*)d_in[1];
  const float* bq = (const float*)d_in[2];
  const float* wk = (const float*)d_in[3];
  const float* bk = (const float*)d_in[4];
  const float* wv = (const float*)d_in[5];
  const float* bv = (const float*)d_in[6];
  const float* wo = (const float*)d_in[7];
  const float* bo = (const float*)d_in[8];
  const float* rel_bias = (const float*)d_in[9];

  char* w = (char*)d_ws;
  ushort_t* xb  = (ushort_t*)w;                       // 15,728,640 B
  ushort_t* wqT = (ushort_t*)(w + 15728640);          // 4 x 524,288 B
  ushort_t* wkT = wqT + 262144;
  ushort_t* wvT = wkT + 262144;
  ushort_t* woT = wvT + 262144;
  ushort_t* qb  = (ushort_t*)(w + 15728640 + 4 * 524288);
  ushort_t* kb  = qb + 7864320;
  ushort_t* vtil = kb + 7864320;                      // tiled V
  ushort_t* ctxb = vtil + 7864320;
  float* cstat = (float*)(w + 80740352);              // rinv [bh][i], 491,520 B
  uint4* pscr = (uint4*)(w + 81264640);               // P scratch, 62,914,560 B
  // rbt (14,745,600 B) aliases xb — xb is dead after qkv_gemm
  float* rbt = (float*)w;

  float* out0 = (float*)d_out;        // [32,480,512]
  float* attn_mean = out0 + 7864320;  // [32,480,480]

  cvt_xw<<<dim3(8704), dim3(256), 0, stream>>>(x, wq, wk, wv, wo, xb, wqT, wkT, wvT, woT);
  qkv_gemm<<<dim3(128, 4, 3), dim3(256), 0, stream>>>(xb, wqT, wkT, wvT, bq, bk, bv,
                                                      qb, kb, vtil);
  cvt_rbt<<<dim3(15, 30, 8), dim3(256), 0, stream>>>(rel_bias, rbt);
  flash_attn<<<dim3(256, 2), dim3(256), 0, stream>>>(qb, kb, vtil, rbt, ctxb, cstat, pscr);
  attn_mean_p<<<dim3(32, 15, 15), dim3(64), 0, stream>>>(pscr, cstat, attn_mean);
  out_gemm<<<dim3(120, 4), dim3(256), 0, stream>>>(ctxb, woT, bo, out0);
}